// Round 2
// baseline (3644.912 us; speedup 1.0000x reference)
//
#include <hip/hip_runtime.h>
#include <hip/hip_bf16.h>

#define NN_NODES 20000
#define NE_EDGES 500000
#define KTOT 48

// ---------------------------------------------------------------------------
// Zero helper
// ---------------------------------------------------------------------------
__global__ void zero_kernel(int* __restrict__ p, int n) {
    int i = blockIdx.x * 256 + threadIdx.x;
    if (i < n) p[i] = 0;
}

// ---------------------------------------------------------------------------
// CSR build: count, scan (single block), fill (records slot per edge)
// ---------------------------------------------------------------------------
__global__ void count_kernel(const int* __restrict__ ei, int* __restrict__ counts) {
    int e = blockIdx.x * 256 + threadIdx.x;
    if (e < NE_EDGES) atomicAdd(&counts[ei[NE_EDGES + e]], 1);
}

__global__ void scan_kernel(const int* __restrict__ counts, int* __restrict__ row_start) {
    __shared__ int part[256];
    const int CH = (NN_NODES + 255) / 256;
    int t = threadIdx.x;
    int begin = t * CH;
    int end = begin + CH;
    if (end > NN_NODES) end = NN_NODES;
    int sum = 0;
    for (int i = begin; i < end && i < NN_NODES; ++i) sum += counts[i];
    part[t] = sum;
    __syncthreads();
    for (int off = 1; off < 256; off <<= 1) {
        int v = (t >= off) ? part[t - off] : 0;
        __syncthreads();
        part[t] += v;
        __syncthreads();
    }
    int run = (t == 0) ? 0 : part[t - 1];
    for (int i = begin; i < end && i < NN_NODES; ++i) {
        row_start[i] = run;
        run += counts[i];
    }
    if (t == 255) row_start[NN_NODES] = part[255];
}

__global__ void fill_kernel(const int* __restrict__ ei, const int* __restrict__ row_start,
                            int* __restrict__ cursor, int* __restrict__ slot_pos) {
    int e = blockIdx.x * 256 + threadIdx.x;
    if (e < NE_EDGES) {
        int d = ei[NE_EDGES + e];
        int p = atomicAdd(&cursor[d], 1);
        slot_pos[e] = row_start[d] + p;
    }
}

// ---------------------------------------------------------------------------
// Edge prep in CSR slot order: srcs[j], dsts[j], bas8[j*8], kidb[j*8]
// ---------------------------------------------------------------------------
__global__ void edge_prep_sorted(const float* __restrict__ pseudo, const int* __restrict__ ei,
                                 const int* __restrict__ slot_pos,
                                 int* __restrict__ srcs, int* __restrict__ dsts,
                                 float* __restrict__ bas8, unsigned char* __restrict__ kidb) {
    int e = blockIdx.x * 256 + threadIdx.x;
    if (e >= NE_EDGES) return;
    const int ksa[3] = {3, 8, 2};
    float frac[3];
    int lo[3];
#pragma unroll
    for (int d = 0; d < 3; ++d) {
        float u = pseudo[e * 3 + d] * (1.0f / 4.5f);
        u = fminf(fmaxf(u, 0.0f), 1.0f);
        float pos = u * (float)(ksa[d] - 1);
        float fl = floorf(pos);
        lo[d] = (int)fl;
        frac[d] = pos - fl;
    }
    int j = slot_pos[e];
    srcs[j] = ei[e];
    dsts[j] = ei[NE_EDGES + e];
#pragma unroll
    for (int s = 0; s < 8; ++s) {
        float w = 1.0f;
        int idx[3];
#pragma unroll
        for (int d = 0; d < 3; ++d) {
            int bit = (s >> d) & 1;
            int id = lo[d] + bit;
            id = max(0, min(id, ksa[d] - 1));
            idx[d] = id;
            w *= bit ? frac[d] : (1.0f - frac[d]);
        }
        bas8[(size_t)j * 8 + s] = w;
        kidb[(size_t)j * 8 + s] = (unsigned char)(idx[0] * 16 + idx[1] * 2 + idx[2]);
    }
}

// ---------------------------------------------------------------------------
// Layer 1: c_in = 1. Global atomic scatter into acc1[N*48], then dense.
// ---------------------------------------------------------------------------
__global__ void scatter1_kernel(const int* __restrict__ srcs, const int* __restrict__ dsts,
                                const float* __restrict__ x, const float* __restrict__ bas8,
                                const unsigned char* __restrict__ kidb,
                                float* __restrict__ acc1) {
    int t = blockIdx.x * 256 + threadIdx.x;
    if (t >= NE_EDGES * 8) return;
    int j = t >> 3;
    atomicAdd(&acc1[dsts[j] * KTOT + kidb[t]], bas8[t] * x[srcs[j]]);
}

__global__ void dense1_kernel(const float* __restrict__ acc1, const float* __restrict__ x,
                              const float* __restrict__ W1, const float* __restrict__ root1,
                              const float* __restrict__ b1, float* __restrict__ h1) {
    __shared__ float w[KTOT * 32];
    for (int l = threadIdx.x; l < KTOT * 32; l += 256) w[l] = W1[l];
    __syncthreads();
    int j = threadIdx.x & 31;
    int nl = threadIdx.x >> 5;
    int n = blockIdx.x * 8 + nl;
    if (n >= NN_NODES) return;
    float s = b1[j] + x[n] * root1[j];
    const float* a = acc1 + n * KTOT;
#pragma unroll
    for (int k = 0; k < KTOT; ++k) s = fmaf(a[k], w[k * 32 + j], s);
    h1[n * 32 + j] = fmaxf(s, 0.0f);
}

// ---------------------------------------------------------------------------
// Accumulate (layers 2/3): wave-level node processing over sorted slots.
// CIN=32: 1 wave/node, intra-wave halves split splines (F=2).
// CIN=64: 2 waves/node split splines (F=2).
// Each lane does 4 LDS atomicAdds per edge. LDS/block = 24 KB -> 6 blocks/CU.
// ---------------------------------------------------------------------------
template <int CIN, int WPN>
__global__ __launch_bounds__(256) void accumulate_kernel(
    const int* __restrict__ srcs, const float* __restrict__ bas8,
    const unsigned int* __restrict__ kidw, const int* __restrict__ row_start,
    const float* __restrict__ h, float* __restrict__ acc, int n0, int mc) {
    constexpr int NPB = 4 / WPN;       // nodes per 256-thread block
    constexpr int ACC = KTOT * CIN;    // accumulator floats per node
    __shared__ float sacc[NPB * ACC];
    int w = threadIdx.x >> 6;
    int lane = threadIdx.x & 63;
    int nl = w / WPN;
    int sub_w = w % WPN;
    int n_local = blockIdx.x * NPB + nl;
    bool active = n_local < mc;
    int n = n0 + n_local;
    float* s_node = sacc + nl * ACC;
    int t = sub_w * 64 + lane;
    for (int l = t; l < ACC; l += WPN * 64) s_node[l] = 0.0f;
    __syncthreads();
    if (active) {
        int ch = lane % CIN;
        int g = sub_w * (64 / CIN) + (lane / CIN);  // spline group 0..1
        int beg = row_start[n], end = row_start[n + 1];
        const float4* basq = (const float4*)bas8;
        int j = beg;
        int sj = (j < end) ? srcs[j] : 0;
        float hv = (j < end) ? h[(size_t)sj * CIN + ch] : 0.0f;
        for (; j < end; ++j) {
            float4 bq = basq[(size_t)j * 2 + g];
            unsigned int kw = kidw[(size_t)j * 2 + g];
            int j1 = j + 1;
            int sn = (j1 < end) ? srcs[j1] : 0;
            float hn = (j1 < end) ? h[(size_t)sn * CIN + ch] : 0.0f;
            atomicAdd(&s_node[((kw) & 63) * CIN + ch], bq.x * hv);
            atomicAdd(&s_node[((kw >> 8) & 63) * CIN + ch], bq.y * hv);
            atomicAdd(&s_node[((kw >> 16) & 63) * CIN + ch], bq.z * hv);
            atomicAdd(&s_node[((kw >> 24) & 63) * CIN + ch], bq.w * hv);
            hv = hn;
        }
    }
    __syncthreads();
    if (active) {
        float* dstp = acc + (size_t)n_local * ACC;
        for (int l = t; l < ACC; l += WPN * 64) dstp[l] = s_node[l];
    }
}

// ---------------------------------------------------------------------------
// Contraction GEMM: out[n0+r, :NN] = relu( A[r,:KK] @ W[KK,NN]
//                                        + Hprev[n0+r,:CP] @ root[CP,NN] + bias )
// ---------------------------------------------------------------------------
#define GBM 128
#define GBN 64
#define GBK 16

__global__ __launch_bounds__(256) void contract_gemm(
    const float* __restrict__ A, int KK, const float* __restrict__ W, int NN,
    const float* __restrict__ Hprev, int CP, const float* __restrict__ root,
    const float* __restrict__ bias, float* __restrict__ out, int n0, int M) {
    __shared__ float As[GBK][GBM + 4];
    __shared__ float Bs[GBK][GBN];
    int bm = blockIdx.x * GBM;
    int bn = blockIdx.y * GBN;
    int tx = threadIdx.x & 15;
    int ty = threadIdx.x >> 4;
    float acc[8][4];
#pragma unroll
    for (int ii = 0; ii < 8; ++ii)
#pragma unroll
        for (int jj = 0; jj < 4; ++jj) acc[ii][jj] = 0.0f;

    for (int k0 = 0; k0 < KK; k0 += GBK) {
#pragma unroll
        for (int it = 0; it < (GBM * GBK) / 256; ++it) {
            int l = threadIdx.x + it * 256;
            int r = l >> 4, kk = l & 15;
            int row = bm + r;
            As[kk][r] = (row < M) ? A[(size_t)row * KK + (k0 + kk)] : 0.0f;
        }
#pragma unroll
        for (int it = 0; it < (GBK * GBN) / 256; ++it) {
            int l = threadIdx.x + it * 256;
            int kk = l >> 6, c = l & 63;
            Bs[kk][c] = W[(size_t)(k0 + kk) * NN + bn + c];
        }
        __syncthreads();
#pragma unroll
        for (int kk = 0; kk < GBK; ++kk) {
            float a[8], b[4];
            *(float4*)&a[0] = *(const float4*)&As[kk][ty * 8];
            *(float4*)&a[4] = *(const float4*)&As[kk][ty * 8 + 4];
            *(float4*)&b[0] = *(const float4*)&Bs[kk][tx * 4];
#pragma unroll
            for (int ii = 0; ii < 8; ++ii)
#pragma unroll
                for (int jj = 0; jj < 4; ++jj) acc[ii][jj] = fmaf(a[ii], b[jj], acc[ii][jj]);
        }
        __syncthreads();
    }

    for (int k0 = 0; k0 < CP; k0 += GBK) {
#pragma unroll
        for (int it = 0; it < (GBM * GBK) / 256; ++it) {
            int l = threadIdx.x + it * 256;
            int r = l >> 4, kk = l & 15;
            int row = bm + r;
            As[kk][r] = (row < M) ? Hprev[(size_t)(n0 + row) * CP + (k0 + kk)] : 0.0f;
        }
#pragma unroll
        for (int it = 0; it < (GBK * GBN) / 256; ++it) {
            int l = threadIdx.x + it * 256;
            int kk = l >> 6, c = l & 63;
            Bs[kk][c] = root[(size_t)(k0 + kk) * NN + bn + c];
        }
        __syncthreads();
#pragma unroll
        for (int kk = 0; kk < GBK; ++kk) {
            float a[8], b[4];
            *(float4*)&a[0] = *(const float4*)&As[kk][ty * 8];
            *(float4*)&a[4] = *(const float4*)&As[kk][ty * 8 + 4];
            *(float4*)&b[0] = *(const float4*)&Bs[kk][tx * 4];
#pragma unroll
            for (int ii = 0; ii < 8; ++ii)
#pragma unroll
                for (int jj = 0; jj < 4; ++jj) acc[ii][jj] = fmaf(a[ii], b[jj], acc[ii][jj]);
        }
        __syncthreads();
    }

#pragma unroll
    for (int ii = 0; ii < 8; ++ii) {
        int row = bm + ty * 8 + ii;
        if (row < M) {
#pragma unroll
            for (int jj = 0; jj < 4; ++jj) {
                int col = bn + tx * 4 + jj;
                float v = acc[ii][jj] + bias[col];
                out[(size_t)(n0 + row) * NN + col] = fmaxf(v, 0.0f);
            }
        }
    }
}

// ---------------------------------------------------------------------------
// log_softmax over rows of out[N,128], in place. One wave per row.
// ---------------------------------------------------------------------------
__global__ void logsoftmax_kernel(float* __restrict__ out) {
    int n = blockIdx.x;
    int lane = threadIdx.x;
    float v0 = out[(size_t)n * 128 + lane];
    float v1 = out[(size_t)n * 128 + 64 + lane];
    float m = fmaxf(v0, v1);
#pragma unroll
    for (int off = 32; off > 0; off >>= 1) m = fmaxf(m, __shfl_xor(m, off));
    float s = expf(v0 - m) + expf(v1 - m);
#pragma unroll
    for (int off = 32; off > 0; off >>= 1) s += __shfl_xor(s, off);
    float lse = m + logf(s);
    out[(size_t)n * 128 + lane] = v0 - lse;
    out[(size_t)n * 128 + 64 + lane] = v1 - lse;
}

// ---------------------------------------------------------------------------
// Launch
// ---------------------------------------------------------------------------
extern "C" void kernel_launch(void* const* d_in, const int* in_sizes, int n_in,
                              void* d_out, int out_size, void* d_ws, size_t ws_size,
                              hipStream_t stream) {
    const float* x = (const float*)d_in[0];
    const int* ei = (const int*)d_in[1];
    const float* pseudo = (const float*)d_in[2];
    const float* W1 = (const float*)d_in[3];
    const float* root1 = (const float*)d_in[4];
    const float* b1 = (const float*)d_in[5];
    const float* W2 = (const float*)d_in[6];
    const float* root2 = (const float*)d_in[7];
    const float* b2 = (const float*)d_in[8];
    const float* W3 = (const float*)d_in[9];
    const float* root3 = (const float*)d_in[10];
    const float* b3 = (const float*)d_in[11];
    float* out = (float*)d_out;
    char* ws = (char*)d_ws;

    const int N = NN_NODES, E = NE_EDGES;
    size_t off = 0;
    auto carve = [&](size_t bytes) {
        size_t p = off;
        off += (bytes + 255) & ~(size_t)255;
        return p;
    };
    int* counts = (int*)(ws + carve((size_t)N * 4 * 2));
    int* cursor = counts + N;
    int* row_start = (int*)(ws + carve((size_t)(N + 1) * 4));
    int* slot_pos = (int*)(ws + carve((size_t)E * 4));
    int* srcs = (int*)(ws + carve((size_t)E * 4));
    int* dsts = (int*)(ws + carve((size_t)E * 4));
    float* bas8 = (float*)(ws + carve((size_t)E * 8 * 4));
    unsigned char* kidb = (unsigned char*)(ws + carve((size_t)E * 8));
    float* h1 = (float*)(ws + carve((size_t)N * 32 * 4));
    float* h2 = (float*)(ws + carve((size_t)N * 64 * 4));
    float* acc1 = (float*)(ws + carve((size_t)N * KTOT * 4));
    size_t rem = (ws_size > off) ? (ws_size - off) : 0;
    float* accbuf = (float*)(ws + off);

    int ch3 = (int)(rem / ((size_t)KTOT * 64 * 4));
    int ch2 = (int)(rem / ((size_t)KTOT * 32 * 4));
    if (ch3 > N) ch3 = N;
    if (ch2 > N) ch2 = N;
    if (ch3 < 1) ch3 = 1;
    if (ch2 < 1) ch2 = 1;

    int egrid = (E + 255) / 256;

    // CSR + sorted edge metadata
    zero_kernel<<<(2 * N + 255) / 256, 256, 0, stream>>>(counts, 2 * N);
    count_kernel<<<egrid, 256, 0, stream>>>(ei, counts);
    scan_kernel<<<1, 256, 0, stream>>>(counts, row_start);
    fill_kernel<<<egrid, 256, 0, stream>>>(ei, row_start, cursor, slot_pos);
    edge_prep_sorted<<<egrid, 256, 0, stream>>>(pseudo, ei, slot_pos, srcs, dsts, bas8, kidb);

    // layer 1
    zero_kernel<<<(N * KTOT + 255) / 256, 256, 0, stream>>>((int*)acc1, N * KTOT);
    scatter1_kernel<<<(E * 8 + 255) / 256, 256, 0, stream>>>(srcs, dsts, x, bas8, kidb, acc1);
    dense1_kernel<<<(N + 7) / 8, 256, 0, stream>>>(acc1, x, W1, root1, b1, h1);

    // layer 2 (CIN=32, WPN=1, 4 nodes/block)
    for (int n0 = 0; n0 < N; n0 += ch2) {
        int mc = N - n0 < ch2 ? N - n0 : ch2;
        accumulate_kernel<32, 1><<<(mc + 3) / 4, 256, 0, stream>>>(
            srcs, bas8, (const unsigned int*)kidb, row_start, h1, accbuf, n0, mc);
        dim3 g((mc + GBM - 1) / GBM, 64 / GBN);
        contract_gemm<<<g, 256, 0, stream>>>(accbuf, KTOT * 32, W2, 64, h1, 32, root2, b2,
                                             h2, n0, mc);
    }

    // layer 3 (CIN=64, WPN=2, 2 nodes/block)
    for (int n0 = 0; n0 < N; n0 += ch3) {
        int mc = N - n0 < ch3 ? N - n0 : ch3;
        accumulate_kernel<64, 2><<<(mc + 1) / 2, 256, 0, stream>>>(
            srcs, bas8, (const unsigned int*)kidb, row_start, h2, accbuf, n0, mc);
        dim3 g((mc + GBM - 1) / GBM, 128 / GBN);
        contract_gemm<<<g, 256, 0, stream>>>(accbuf, KTOT * 64, W3, 128, h2, 64, root3, b3,
                                             out, n0, mc);
    }

    logsoftmax_kernel<<<N, 64, 0, stream>>>(out);
}

// Round 3
// 1974.806 us; speedup vs baseline: 1.8457x; 1.8457x over previous
//
#include <hip/hip_runtime.h>
#include <hip/hip_bf16.h>

#define NN_NODES 20000
#define NE_EDGES 500000
#define KTOT 48

// ---------------------------------------------------------------------------
// Zero helper
// ---------------------------------------------------------------------------
__global__ void zero_kernel(int* __restrict__ p, int n) {
    int i = blockIdx.x * 256 + threadIdx.x;
    if (i < n) p[i] = 0;
}

// ---------------------------------------------------------------------------
// CSR build: count, scan (single block), fill (records slot per edge)
// ---------------------------------------------------------------------------
__global__ void count_kernel(const int* __restrict__ ei, int* __restrict__ counts) {
    int e = blockIdx.x * 256 + threadIdx.x;
    if (e < NE_EDGES) atomicAdd(&counts[ei[NE_EDGES + e]], 1);
}

__global__ void scan_kernel(const int* __restrict__ counts, int* __restrict__ row_start) {
    __shared__ int part[256];
    const int CH = (NN_NODES + 255) / 256;
    int t = threadIdx.x;
    int begin = t * CH;
    int end = begin + CH;
    if (end > NN_NODES) end = NN_NODES;
    int sum = 0;
    for (int i = begin; i < end && i < NN_NODES; ++i) sum += counts[i];
    part[t] = sum;
    __syncthreads();
    for (int off = 1; off < 256; off <<= 1) {
        int v = (t >= off) ? part[t - off] : 0;
        __syncthreads();
        part[t] += v;
        __syncthreads();
    }
    int run = (t == 0) ? 0 : part[t - 1];
    for (int i = begin; i < end && i < NN_NODES; ++i) {
        row_start[i] = run;
        run += counts[i];
    }
    if (t == 255) row_start[NN_NODES] = part[255];
}

__global__ void fill_kernel(const int* __restrict__ ei, const int* __restrict__ row_start,
                            int* __restrict__ cursor, int* __restrict__ slot_pos) {
    int e = blockIdx.x * 256 + threadIdx.x;
    if (e < NE_EDGES) {
        int d = ei[NE_EDGES + e];
        int p = atomicAdd(&cursor[d], 1);
        slot_pos[e] = row_start[d] + p;
    }
}

// ---------------------------------------------------------------------------
// Edge prep in CSR slot order: srcs[j], bas8[j*8], kidb[j*8].
// IMPORTANT: all 8 kidx of an edge are made pairwise DISTINCT by redirecting
// clamped corners (whose basis weight is exactly 0) to lo-1 instead of lo.
// This makes non-atomic read-all/write-all LDS accumulation race-free.
// ---------------------------------------------------------------------------
__global__ void edge_prep_sorted(const float* __restrict__ pseudo, const int* __restrict__ ei,
                                 const int* __restrict__ slot_pos,
                                 int* __restrict__ srcs,
                                 float* __restrict__ bas8, unsigned char* __restrict__ kidb) {
    int e = blockIdx.x * 256 + threadIdx.x;
    if (e >= NE_EDGES) return;
    const int ksa[3] = {3, 8, 2};
    float frac[3];
    int id_lo[3], id_hi[3];
#pragma unroll
    for (int d = 0; d < 3; ++d) {
        float u = pseudo[e * 3 + d] * (1.0f / 4.5f);
        u = fminf(fmaxf(u, 0.0f), 1.0f);
        float pos = u * (float)(ksa[d] - 1);
        float fl = floorf(pos);
        int lo = (int)fl;
        frac[d] = pos - fl;
        id_lo[d] = lo;
        // lo+1 out of range only when pos == ks-1 exactly => frac == 0, so the
        // "hi" corner has zero weight; redirect it anywhere distinct (lo-1).
        id_hi[d] = (lo + 1 <= ksa[d] - 1) ? lo + 1 : lo - 1;
    }
    int j = slot_pos[e];
    srcs[j] = ei[e];
#pragma unroll
    for (int s = 0; s < 8; ++s) {
        float w = 1.0f;
        int k = 0;
        const int strides[3] = {16, 2, 1};
#pragma unroll
        for (int d = 0; d < 3; ++d) {
            int bit = (s >> d) & 1;
            k += (bit ? id_hi[d] : id_lo[d]) * strides[d];
            w *= bit ? frac[d] : (1.0f - frac[d]);
        }
        bas8[(size_t)j * 8 + s] = w;
        kidb[(size_t)j * 8 + s] = (unsigned char)k;
    }
}

// ---------------------------------------------------------------------------
// Layer 1 accumulate (c_in = 1): one wave per node, lane == k, pure register
// accumulation (no atomics, no LDS).
// ---------------------------------------------------------------------------
__global__ __launch_bounds__(256) void layer1_acc_kernel(
    const int* __restrict__ srcs, const float* __restrict__ bas8,
    const unsigned char* __restrict__ kidb, const int* __restrict__ row_start,
    const float* __restrict__ x, float* __restrict__ acc1) {
    int w = threadIdx.x >> 6, lane = threadIdx.x & 63;
    int n = blockIdx.x * 4 + w;
    if (n >= NN_NODES) return;
    int beg = row_start[n], end = row_start[n + 1];
    float a = 0.0f;
    int j = beg;
    float xv = 0.0f;
    if (j < end) xv = x[srcs[j]];
    for (; j < end; ++j) {
        float xc = xv;
        if (j + 1 < end) xv = x[srcs[j + 1]];
        const float* bp = bas8 + (size_t)j * 8;
        const unsigned char* kp = kidb + (size_t)j * 8;
#pragma unroll
        for (int s = 0; s < 8; ++s) a += (kp[s] == lane) ? bp[s] * xc : 0.0f;
    }
    if (lane < KTOT) acc1[n * KTOT + lane] = a;
}

__global__ void dense1_kernel(const float* __restrict__ acc1, const float* __restrict__ x,
                              const float* __restrict__ W1, const float* __restrict__ root1,
                              const float* __restrict__ b1, float* __restrict__ h1) {
    __shared__ float w[KTOT * 32];
    for (int l = threadIdx.x; l < KTOT * 32; l += 256) w[l] = W1[l];
    __syncthreads();
    int j = threadIdx.x & 31;
    int nl = threadIdx.x >> 5;
    int n = blockIdx.x * 8 + nl;
    if (n >= NN_NODES) return;
    float s = b1[j] + x[n] * root1[j];
    const float* a = acc1 + n * KTOT;
#pragma unroll
    for (int k = 0; k < KTOT; ++k) s = fmaf(a[k], w[k * 32 + j], s);
    h1[n * 32 + j] = fmaxf(s, 0.0f);
}

// ---------------------------------------------------------------------------
// Accumulate (layers 2/3): one WAVE per node. Lane owns a float4 channel
// slice; spline-groups within the wave hit distinct k rows (guaranteed by
// edge prep). NON-ATOMIC LDS read-modify-write:
//   per edge: read all SPL old values -> fma -> write all SPL.
// Cross-edge/cross-lane ordering is safe via the in-order per-wave DS pipe.
// No __syncthreads needed: LDS regions are wave-private.
// ---------------------------------------------------------------------------
template <int CIN>
__global__ __launch_bounds__(256) void accumulate_kernel(
    const int* __restrict__ srcs, const float* __restrict__ bas8,
    const unsigned char* __restrict__ kidb, const int* __restrict__ row_start,
    const float* __restrict__ h, float* __restrict__ acc, int n0, int mc) {
    constexpr int ACC = KTOT * CIN;     // floats per node
    constexpr int LPS = CIN / 4;        // lanes spanning the channel dim
    constexpr int NGRP = 64 / LPS;      // spline groups per wave
    constexpr int SPL = 8 / NGRP;       // splines per lane
    __shared__ float sacc[4 * ACC];
    int w = threadIdx.x >> 6, lane = threadIdx.x & 63;
    int n_local = blockIdx.x * 4 + w;
    if (n_local >= mc) return;
    int n = n0 + n_local;
    float4* s_node = (float4*)(sacc + w * ACC);
    for (int l = lane; l < ACC / 4; l += 64) s_node[l] = make_float4(0.f, 0.f, 0.f, 0.f);
    int chq = lane % LPS;      // float4 index within channel dim
    int sg = lane / LPS;       // spline group
    int beg = row_start[n], end = row_start[n + 1];
    int j = beg;
    float4 hv = make_float4(0.f, 0.f, 0.f, 0.f);
    if (j < end) {
        int s0 = srcs[j];
        hv = *(const float4*)&h[(size_t)s0 * CIN + chq * 4];
    }
    for (; j < end; ++j) {
        float4 hc = hv;
        int j1 = j + 1;
        if (j1 < end) {
            int s1 = srcs[j1];
            hv = *(const float4*)&h[(size_t)s1 * CIN + chq * 4];
        }
        const float* bp = bas8 + (size_t)j * 8;
        const unsigned char* kp = kidb + (size_t)j * 8;
        float bs[SPL];
        int ks[SPL];
        float4 ov[SPL];
#pragma unroll
        for (int t = 0; t < SPL; ++t) {
            int s = sg + t * NGRP;
            bs[t] = bp[s];
            ks[t] = kp[s];
        }
#pragma unroll
        for (int t = 0; t < SPL; ++t) ov[t] = s_node[ks[t] * LPS + chq];
#pragma unroll
        for (int t = 0; t < SPL; ++t) {
            float b = bs[t];
            ov[t].x = fmaf(b, hc.x, ov[t].x);
            ov[t].y = fmaf(b, hc.y, ov[t].y);
            ov[t].z = fmaf(b, hc.z, ov[t].z);
            ov[t].w = fmaf(b, hc.w, ov[t].w);
            s_node[ks[t] * LPS + chq] = ov[t];
        }
    }
    float4* dstp = (float4*)(acc + (size_t)n_local * ACC);
    for (int l = lane; l < ACC / 4; l += 64) dstp[l] = s_node[l];
}

// ---------------------------------------------------------------------------
// Contraction GEMM: out[n0+r, :NN] = relu( A[r,:KK] @ W[KK,NN]
//                                        + Hprev[n0+r,:CP] @ root[CP,NN] + bias )
// ---------------------------------------------------------------------------
#define GBM 128
#define GBN 64
#define GBK 16

__global__ __launch_bounds__(256) void contract_gemm(
    const float* __restrict__ A, int KK, const float* __restrict__ W, int NN,
    const float* __restrict__ Hprev, int CP, const float* __restrict__ root,
    const float* __restrict__ bias, float* __restrict__ out, int n0, int M) {
    __shared__ float As[GBK][GBM + 4];
    __shared__ float Bs[GBK][GBN];
    int bm = blockIdx.x * GBM;
    int bn = blockIdx.y * GBN;
    int tx = threadIdx.x & 15;
    int ty = threadIdx.x >> 4;
    float acc[8][4];
#pragma unroll
    for (int ii = 0; ii < 8; ++ii)
#pragma unroll
        for (int jj = 0; jj < 4; ++jj) acc[ii][jj] = 0.0f;

    for (int k0 = 0; k0 < KK; k0 += GBK) {
#pragma unroll
        for (int it = 0; it < (GBM * GBK) / 256; ++it) {
            int l = threadIdx.x + it * 256;
            int r = l >> 4, kk = l & 15;
            int row = bm + r;
            As[kk][r] = (row < M) ? A[(size_t)row * KK + (k0 + kk)] : 0.0f;
        }
#pragma unroll
        for (int it = 0; it < (GBK * GBN) / 256; ++it) {
            int l = threadIdx.x + it * 256;
            int kk = l >> 6, c = l & 63;
            Bs[kk][c] = W[(size_t)(k0 + kk) * NN + bn + c];
        }
        __syncthreads();
#pragma unroll
        for (int kk = 0; kk < GBK; ++kk) {
            float a[8], b[4];
            *(float4*)&a[0] = *(const float4*)&As[kk][ty * 8];
            *(float4*)&a[4] = *(const float4*)&As[kk][ty * 8 + 4];
            *(float4*)&b[0] = *(const float4*)&Bs[kk][tx * 4];
#pragma unroll
            for (int ii = 0; ii < 8; ++ii)
#pragma unroll
                for (int jj = 0; jj < 4; ++jj) acc[ii][jj] = fmaf(a[ii], b[jj], acc[ii][jj]);
        }
        __syncthreads();
    }

    for (int k0 = 0; k0 < CP; k0 += GBK) {
#pragma unroll
        for (int it = 0; it < (GBM * GBK) / 256; ++it) {
            int l = threadIdx.x + it * 256;
            int r = l >> 4, kk = l & 15;
            int row = bm + r;
            As[kk][r] = (row < M) ? Hprev[(size_t)(n0 + row) * CP + (k0 + kk)] : 0.0f;
        }
#pragma unroll
        for (int it = 0; it < (GBK * GBN) / 256; ++it) {
            int l = threadIdx.x + it * 256;
            int kk = l >> 6, c = l & 63;
            Bs[kk][c] = root[(size_t)(k0 + kk) * NN + bn + c];
        }
        __syncthreads();
#pragma unroll
        for (int kk = 0; kk < GBK; ++kk) {
            float a[8], b[4];
            *(float4*)&a[0] = *(const float4*)&As[kk][ty * 8];
            *(float4*)&a[4] = *(const float4*)&As[kk][ty * 8 + 4];
            *(float4*)&b[0] = *(const float4*)&Bs[kk][tx * 4];
#pragma unroll
            for (int ii = 0; ii < 8; ++ii)
#pragma unroll
                for (int jj = 0; jj < 4; ++jj) acc[ii][jj] = fmaf(a[ii], b[jj], acc[ii][jj]);
        }
        __syncthreads();
    }

#pragma unroll
    for (int ii = 0; ii < 8; ++ii) {
        int row = bm + ty * 8 + ii;
        if (row < M) {
#pragma unroll
            for (int jj = 0; jj < 4; ++jj) {
                int col = bn + tx * 4 + jj;
                float v = acc[ii][jj] + bias[col];
                out[(size_t)(n0 + row) * NN + col] = fmaxf(v, 0.0f);
            }
        }
    }
}

// ---------------------------------------------------------------------------
// log_softmax over rows of out[N,128], in place. One wave per row.
// ---------------------------------------------------------------------------
__global__ void logsoftmax_kernel(float* __restrict__ out) {
    int n = blockIdx.x;
    int lane = threadIdx.x;
    float v0 = out[(size_t)n * 128 + lane];
    float v1 = out[(size_t)n * 128 + 64 + lane];
    float m = fmaxf(v0, v1);
#pragma unroll
    for (int off = 32; off > 0; off >>= 1) m = fmaxf(m, __shfl_xor(m, off));
    float s = expf(v0 - m) + expf(v1 - m);
#pragma unroll
    for (int off = 32; off > 0; off >>= 1) s += __shfl_xor(s, off);
    float lse = m + logf(s);
    out[(size_t)n * 128 + lane] = v0 - lse;
    out[(size_t)n * 128 + 64 + lane] = v1 - lse;
}

// ---------------------------------------------------------------------------
// Launch
// ---------------------------------------------------------------------------
extern "C" void kernel_launch(void* const* d_in, const int* in_sizes, int n_in,
                              void* d_out, int out_size, void* d_ws, size_t ws_size,
                              hipStream_t stream) {
    const float* x = (const float*)d_in[0];
    const int* ei = (const int*)d_in[1];
    const float* pseudo = (const float*)d_in[2];
    const float* W1 = (const float*)d_in[3];
    const float* root1 = (const float*)d_in[4];
    const float* b1 = (const float*)d_in[5];
    const float* W2 = (const float*)d_in[6];
    const float* root2 = (const float*)d_in[7];
    const float* b2 = (const float*)d_in[8];
    const float* W3 = (const float*)d_in[9];
    const float* root3 = (const float*)d_in[10];
    const float* b3 = (const float*)d_in[11];
    float* out = (float*)d_out;
    char* ws = (char*)d_ws;

    const int N = NN_NODES, E = NE_EDGES;
    size_t off = 0;
    auto carve = [&](size_t bytes) {
        size_t p = off;
        off += (bytes + 255) & ~(size_t)255;
        return p;
    };
    int* counts = (int*)(ws + carve((size_t)N * 4 * 2));
    int* cursor = counts + N;
    int* row_start = (int*)(ws + carve((size_t)(N + 1) * 4));
    int* slot_pos = (int*)(ws + carve((size_t)E * 4));
    int* srcs = (int*)(ws + carve((size_t)E * 4));
    float* bas8 = (float*)(ws + carve((size_t)E * 8 * 4));
    unsigned char* kidb = (unsigned char*)(ws + carve((size_t)E * 8));
    float* h1 = (float*)(ws + carve((size_t)N * 32 * 4));
    float* h2 = (float*)(ws + carve((size_t)N * 64 * 4));
    float* acc1 = (float*)(ws + carve((size_t)N * KTOT * 4));
    size_t rem = (ws_size > off) ? (ws_size - off) : 0;
    float* accbuf = (float*)(ws + off);

    int ch3 = (int)(rem / ((size_t)KTOT * 64 * 4));
    int ch2 = (int)(rem / ((size_t)KTOT * 32 * 4));
    if (ch3 > N) ch3 = N;
    if (ch2 > N) ch2 = N;
    if (ch3 < 1) ch3 = 1;
    if (ch2 < 1) ch2 = 1;

    int egrid = (E + 255) / 256;

    // CSR + sorted edge metadata
    zero_kernel<<<(2 * N + 255) / 256, 256, 0, stream>>>(counts, 2 * N);
    count_kernel<<<egrid, 256, 0, stream>>>(ei, counts);
    scan_kernel<<<1, 256, 0, stream>>>(counts, row_start);
    fill_kernel<<<egrid, 256, 0, stream>>>(ei, row_start, cursor, slot_pos);
    edge_prep_sorted<<<egrid, 256, 0, stream>>>(pseudo, ei, slot_pos, srcs, bas8, kidb);

    // layer 1 (register accumulate, no atomics)
    layer1_acc_kernel<<<(N + 3) / 4, 256, 0, stream>>>(srcs, bas8, kidb, row_start, x, acc1);
    dense1_kernel<<<(N + 7) / 8, 256, 0, stream>>>(acc1, x, W1, root1, b1, h1);

    // layer 2 (CIN=32): wave-per-node, non-atomic LDS RMW
    for (int n0 = 0; n0 < N; n0 += ch2) {
        int mc = N - n0 < ch2 ? N - n0 : ch2;
        accumulate_kernel<32><<<(mc + 3) / 4, 256, 0, stream>>>(
            srcs, bas8, kidb, row_start, h1, accbuf, n0, mc);
        dim3 g((mc + GBM - 1) / GBM, 64 / GBN);
        contract_gemm<<<g, 256, 0, stream>>>(accbuf, KTOT * 32, W2, 64, h1, 32, root2, b2,
                                             h2, n0, mc);
    }

    // layer 3 (CIN=64)
    for (int n0 = 0; n0 < N; n0 += ch3) {
        int mc = N - n0 < ch3 ? N - n0 : ch3;
        accumulate_kernel<64><<<(mc + 3) / 4, 256, 0, stream>>>(
            srcs, bas8, kidb, row_start, h2, accbuf, n0, mc);
        dim3 g((mc + GBM - 1) / GBM, 128 / GBN);
        contract_gemm<<<g, 256, 0, stream>>>(accbuf, KTOT * 64, W3, 128, h2, 64, root3, b3,
                                             out, n0, mc);
    }

    logsoftmax_kernel<<<N, 64, 0, stream>>>(out);
}

// Round 4
// 730.137 us; speedup vs baseline: 4.9921x; 2.7047x over previous
//
#include <hip/hip_runtime.h>
#include <hip/hip_bf16.h>

#define NN_NODES 20000
#define NE_EDGES 500000
#define KTOT 48

typedef __bf16 bf16x8 __attribute__((ext_vector_type(8)));
typedef float f32x4 __attribute__((ext_vector_type(4)));

__device__ inline unsigned short bf16_rne(float x) {
    unsigned int u = __float_as_uint(x);
    u = (u + 0x7fffu + ((u >> 16) & 1u)) >> 16;
    return (unsigned short)u;
}
__device__ inline unsigned int pack_bf16x2(float a, float b) {
    return (unsigned int)bf16_rne(a) | ((unsigned int)bf16_rne(b) << 16);
}

// ---------------------------------------------------------------------------
// Zero helper
// ---------------------------------------------------------------------------
__global__ void zero_kernel(int* __restrict__ p, int n) {
    int i = blockIdx.x * 256 + threadIdx.x;
    if (i < n) p[i] = 0;
}

// ---------------------------------------------------------------------------
// CSR build
// ---------------------------------------------------------------------------
__global__ void count_kernel(const int* __restrict__ ei, int* __restrict__ counts) {
    int e = blockIdx.x * 256 + threadIdx.x;
    if (e < NE_EDGES) atomicAdd(&counts[ei[NE_EDGES + e]], 1);
}

__global__ void scan_kernel(const int* __restrict__ counts, int* __restrict__ row_start) {
    __shared__ int part[256];
    const int CH = (NN_NODES + 255) / 256;
    int t = threadIdx.x;
    int begin = t * CH;
    int end = begin + CH;
    if (end > NN_NODES) end = NN_NODES;
    int sum = 0;
    for (int i = begin; i < end && i < NN_NODES; ++i) sum += counts[i];
    part[t] = sum;
    __syncthreads();
    for (int off = 1; off < 256; off <<= 1) {
        int v = (t >= off) ? part[t - off] : 0;
        __syncthreads();
        part[t] += v;
        __syncthreads();
    }
    int run = (t == 0) ? 0 : part[t - 1];
    for (int i = begin; i < end && i < NN_NODES; ++i) {
        row_start[i] = run;
        run += counts[i];
    }
    if (t == 255) row_start[NN_NODES] = part[255];
}

__global__ void fill_kernel(const int* __restrict__ ei, const int* __restrict__ row_start,
                            int* __restrict__ cursor, int* __restrict__ slot_pos) {
    int e = blockIdx.x * 256 + threadIdx.x;
    if (e < NE_EDGES) {
        int d = ei[NE_EDGES + e];
        int p = atomicAdd(&cursor[d], 1);
        slot_pos[e] = row_start[d] + p;
    }
}

// ---------------------------------------------------------------------------
// Edge prep (CSR slot order). All 8 kidx of an edge pairwise DISTINCT
// (clamped zero-weight corners redirected) => non-atomic LDS RMW is safe.
// ---------------------------------------------------------------------------
__global__ void edge_prep_sorted(const float* __restrict__ pseudo, const int* __restrict__ ei,
                                 const int* __restrict__ slot_pos,
                                 int* __restrict__ srcs,
                                 float* __restrict__ bas8, unsigned char* __restrict__ kidb) {
    int e = blockIdx.x * 256 + threadIdx.x;
    if (e >= NE_EDGES) return;
    const int ksa[3] = {3, 8, 2};
    float frac[3];
    int id_lo[3], id_hi[3];
#pragma unroll
    for (int d = 0; d < 3; ++d) {
        float u = pseudo[e * 3 + d] * (1.0f / 4.5f);
        u = fminf(fmaxf(u, 0.0f), 1.0f);
        float pos = u * (float)(ksa[d] - 1);
        float fl = floorf(pos);
        int lo = (int)fl;
        frac[d] = pos - fl;
        id_lo[d] = lo;
        id_hi[d] = (lo + 1 <= ksa[d] - 1) ? lo + 1 : lo - 1;
    }
    int j = slot_pos[e];
    srcs[j] = ei[e];
#pragma unroll
    for (int s = 0; s < 8; ++s) {
        float w = 1.0f;
        int k = 0;
        const int strides[3] = {16, 2, 1};
#pragma unroll
        for (int d = 0; d < 3; ++d) {
            int bit = (s >> d) & 1;
            k += (bit ? id_hi[d] : id_lo[d]) * strides[d];
            w *= bit ? frac[d] : (1.0f - frac[d]);
        }
        bas8[(size_t)j * 8 + s] = w;
        kidb[(size_t)j * 8 + s] = (unsigned char)k;
    }
}

// ---------------------------------------------------------------------------
// Layer 1 accumulate (c_in = 1): wave per node, lane == k, register acc.
// ---------------------------------------------------------------------------
__global__ __launch_bounds__(256) void layer1_acc_kernel(
    const int* __restrict__ srcs, const float* __restrict__ bas8,
    const unsigned char* __restrict__ kidb, const int* __restrict__ row_start,
    const float* __restrict__ x, float* __restrict__ acc1) {
    int w = threadIdx.x >> 6, lane = threadIdx.x & 63;
    int n = blockIdx.x * 4 + w;
    if (n >= NN_NODES) return;
    int beg = row_start[n], end = row_start[n + 1];
    float a = 0.0f;
    int j = beg;
    float xv = 0.0f;
    if (j < end) xv = x[srcs[j]];
    for (; j < end; ++j) {
        float xc = xv;
        if (j + 1 < end) xv = x[srcs[j + 1]];
        const float* bp = bas8 + (size_t)j * 8;
        const unsigned char* kp = kidb + (size_t)j * 8;
#pragma unroll
        for (int s = 0; s < 8; ++s) a += (kp[s] == lane) ? bp[s] * xc : 0.0f;
    }
    if (lane < KTOT) acc1[n * KTOT + lane] = a;
}

__global__ void dense1_kernel(const float* __restrict__ acc1, const float* __restrict__ x,
                              const float* __restrict__ W1, const float* __restrict__ root1,
                              const float* __restrict__ b1, float* __restrict__ h1) {
    __shared__ float w[KTOT * 32];
    for (int l = threadIdx.x; l < KTOT * 32; l += 256) w[l] = W1[l];
    __syncthreads();
    int j = threadIdx.x & 31;
    int nl = threadIdx.x >> 5;
    int n = blockIdx.x * 8 + nl;
    if (n >= NN_NODES) return;
    float s = b1[j] + x[n] * root1[j];
    const float* a = acc1 + n * KTOT;
#pragma unroll
    for (int k = 0; k < KTOT; ++k) s = fmaf(a[k], w[k * 32 + j], s);
    h1[n * 32 + j] = fmaxf(s, 0.0f);
}

// ---------------------------------------------------------------------------
// Accumulate (layers 2/3): wave per node, non-atomic LDS RMW; stores the
// A-row in BF16: [acc(KTOT*CIN) | h_prev(CIN)] -> Kp = 49*CIN bf16 per node.
// ---------------------------------------------------------------------------
template <int CIN>
__global__ __launch_bounds__(256) void accumulate_kernel(
    const int* __restrict__ srcs, const float* __restrict__ bas8,
    const unsigned char* __restrict__ kidb, const int* __restrict__ row_start,
    const float* __restrict__ h, unsigned short* __restrict__ abuf, int n0, int mc) {
    constexpr int ACC = KTOT * CIN;
    constexpr int KP = ACC + CIN;
    constexpr int LPS = CIN / 4;
    constexpr int NGRP = 64 / LPS;
    constexpr int SPL = 8 / NGRP;
    __shared__ float sacc[4 * ACC];
    int w = threadIdx.x >> 6, lane = threadIdx.x & 63;
    int n_local = blockIdx.x * 4 + w;
    if (n_local >= mc) return;
    int n = n0 + n_local;
    float4* s_node = (float4*)(sacc + w * ACC);
    for (int l = lane; l < ACC / 4; l += 64) s_node[l] = make_float4(0.f, 0.f, 0.f, 0.f);
    int chq = lane % LPS;
    int sg = lane / LPS;
    int beg = row_start[n], end = row_start[n + 1];
    int j = beg;
    float4 hv = make_float4(0.f, 0.f, 0.f, 0.f);
    if (j < end) {
        int s0 = srcs[j];
        hv = *(const float4*)&h[(size_t)s0 * CIN + chq * 4];
    }
    for (; j < end; ++j) {
        float4 hc = hv;
        int j1 = j + 1;
        if (j1 < end) {
            int s1 = srcs[j1];
            hv = *(const float4*)&h[(size_t)s1 * CIN + chq * 4];
        }
        const float* bp = bas8 + (size_t)j * 8;
        const unsigned char* kp = kidb + (size_t)j * 8;
        float bs[SPL];
        int ks[SPL];
        float4 ov[SPL];
#pragma unroll
        for (int t = 0; t < SPL; ++t) {
            int s = sg + t * NGRP;
            bs[t] = bp[s];
            ks[t] = kp[s];
        }
#pragma unroll
        for (int t = 0; t < SPL; ++t) ov[t] = s_node[ks[t] * LPS + chq];
#pragma unroll
        for (int t = 0; t < SPL; ++t) {
            float b = bs[t];
            ov[t].x = fmaf(b, hc.x, ov[t].x);
            ov[t].y = fmaf(b, hc.y, ov[t].y);
            ov[t].z = fmaf(b, hc.z, ov[t].z);
            ov[t].w = fmaf(b, hc.w, ov[t].w);
            s_node[ks[t] * LPS + chq] = ov[t];
        }
    }
    // store bf16 row: acc part then h_prev tail
    unsigned int* dstp = (unsigned int*)abuf + (size_t)n_local * (KP / 2);
    const float2* s2 = (const float2*)s_node;
    for (int l = lane; l < ACC / 2; l += 64) {
        float2 v = s2[l];
        dstp[l] = pack_bf16x2(v.x, v.y);
    }
    const float2* hrow = (const float2*)(h + (size_t)n * CIN);
    if (lane < CIN / 2) {
        float2 v = hrow[lane];
        dstp[ACC / 2 + lane] = pack_bf16x2(v.x, v.y);
    }
}

// ---------------------------------------------------------------------------
// Pack W' = [W(KK rows); root(CP rows)] (fp32, row-major [Kp][NN]) into MFMA
// B-fragment order: elem((t,c,l,j)) = W'[t*32 + (l>>4)*8 + j][c*16 + (l&15)].
// One thread per (t,c,l), writes 8 bf16 = 16 B.
// ---------------------------------------------------------------------------
__global__ void pack_w_kernel(const float* __restrict__ W, const float* __restrict__ root,
                              int KK, int NN, int total, unsigned short* __restrict__ Wp) {
    int tid = blockIdx.x * 256 + threadIdx.x;
    if (tid >= total) return;
    int nct = NN >> 4;
    int l = tid & 63;
    int c = (tid >> 6) % nct;
    int t = tid / (64 * nct);
    int n = c * 16 + (l & 15);
    int kbase = t * 32 + ((l >> 4) << 3);
    unsigned short vals[8];
#pragma unroll
    for (int jj = 0; jj < 8; ++jj) {
        int k = kbase + jj;
        float v = (k < KK) ? W[(size_t)k * NN + n] : root[(size_t)(k - KK) * NN + n];
        vals[jj] = bf16_rne(v);
    }
    *(uint4*)&Wp[(size_t)tid * 8] = *(uint4*)vals;
}

// ---------------------------------------------------------------------------
// MFMA GEMM: out[n0+r, :NN] = relu( Arow[r,:Kp](bf16) @ W'[Kp,NN] + bias ).
// Block = 4 waves = 64 rows; each wave: 16 rows x NN cols via 16x16x32 bf16
// MFMA. B-frags read coalesced from packed Wp; A-frags 16B/lane from bf16 rows.
// ---------------------------------------------------------------------------
template <int NCT>
__global__ __launch_bounds__(256) void mfma_gemm(
    const unsigned short* __restrict__ A, const unsigned short* __restrict__ Wp,
    const float* __restrict__ bias, float* __restrict__ out,
    int Kp, int n0, int mc) {
    constexpr int NN = NCT * 16;
    int w = threadIdx.x >> 6, lane = threadIdx.x & 63;
    int row_local = blockIdx.x * 64 + w * 16 + (lane & 15);
    int row_c = min(row_local, mc - 1);
    const unsigned short* arow = A + (size_t)row_c * Kp + ((lane >> 4) << 3);
    const uint4* wpq = (const uint4*)Wp;
    f32x4 acc[NCT] = {};
    int tsteps = Kp >> 5;
    for (int t = 0; t < tsteps; ++t) {
        uint4 araw = *(const uint4*)(arow + t * 32);
        bf16x8 af = __builtin_bit_cast(bf16x8, araw);
        const uint4* bbase = wpq + ((size_t)t * NCT) * 64 + lane;
#pragma unroll
        for (int c = 0; c < NCT; ++c) {
            uint4 braw = bbase[c * 64];
            bf16x8 bfr = __builtin_bit_cast(bf16x8, braw);
            acc[c] = __builtin_amdgcn_mfma_f32_16x16x32_bf16(af, bfr, acc[c], 0, 0, 0);
        }
    }
    int col0 = lane & 15;
    int rbase = blockIdx.x * 64 + w * 16 + ((lane >> 4) << 2);
#pragma unroll
    for (int c = 0; c < NCT; ++c) {
        int col = c * 16 + col0;
        float bv = bias[col];
#pragma unroll
        for (int r = 0; r < 4; ++r) {
            int rowo = rbase + r;
            if (rowo < mc)
                out[(size_t)(n0 + rowo) * NN + col] = fmaxf(acc[c][r] + bv, 0.0f);
        }
    }
}

// ---------------------------------------------------------------------------
// log_softmax over rows of out[N,128], in place. One wave per row.
// ---------------------------------------------------------------------------
__global__ void logsoftmax_kernel(float* __restrict__ out) {
    int n = blockIdx.x;
    int lane = threadIdx.x;
    float v0 = out[(size_t)n * 128 + lane];
    float v1 = out[(size_t)n * 128 + 64 + lane];
    float m = fmaxf(v0, v1);
#pragma unroll
    for (int off = 32; off > 0; off >>= 1) m = fmaxf(m, __shfl_xor(m, off));
    float s = expf(v0 - m) + expf(v1 - m);
#pragma unroll
    for (int off = 32; off > 0; off >>= 1) s += __shfl_xor(s, off);
    float lse = m + logf(s);
    out[(size_t)n * 128 + lane] = v0 - lse;
    out[(size_t)n * 128 + 64 + lane] = v1 - lse;
}

// ---------------------------------------------------------------------------
// Launch
// ---------------------------------------------------------------------------
extern "C" void kernel_launch(void* const* d_in, const int* in_sizes, int n_in,
                              void* d_out, int out_size, void* d_ws, size_t ws_size,
                              hipStream_t stream) {
    const float* x = (const float*)d_in[0];
    const int* ei = (const int*)d_in[1];
    const float* pseudo = (const float*)d_in[2];
    const float* W1 = (const float*)d_in[3];
    const float* root1 = (const float*)d_in[4];
    const float* b1 = (const float*)d_in[5];
    const float* W2 = (const float*)d_in[6];
    const float* root2 = (const float*)d_in[7];
    const float* b2 = (const float*)d_in[8];
    const float* W3 = (const float*)d_in[9];
    const float* root3 = (const float*)d_in[10];
    const float* b3 = (const float*)d_in[11];
    float* out = (float*)d_out;
    char* ws = (char*)d_ws;

    const int N = NN_NODES, E = NE_EDGES;
    const int Kp2 = 49 * 32;   // 1568
    const int Kp3 = 49 * 64;   // 3136
    size_t off = 0;
    auto carve = [&](size_t bytes) {
        size_t p = off;
        off += (bytes + 255) & ~(size_t)255;
        return p;
    };
    int* counts = (int*)(ws + carve((size_t)N * 4 * 2));
    int* cursor = counts + N;
    int* row_start = (int*)(ws + carve((size_t)(N + 1) * 4));
    int* slot_pos = (int*)(ws + carve((size_t)E * 4));
    int* srcs = (int*)(ws + carve((size_t)E * 4));
    float* bas8 = (float*)(ws + carve((size_t)E * 8 * 4));
    unsigned char* kidb = (unsigned char*)(ws + carve((size_t)E * 8));
    float* h1 = (float*)(ws + carve((size_t)N * 32 * 4));
    float* h2 = (float*)(ws + carve((size_t)N * 64 * 4));
    float* acc1 = (float*)(ws + carve((size_t)N * KTOT * 4));
    unsigned short* Wp2 = (unsigned short*)(ws + carve((size_t)Kp2 * 64 * 2));
    unsigned short* Wp3 = (unsigned short*)(ws + carve((size_t)Kp3 * 128 * 2));
    size_t rem = (ws_size > off) ? (ws_size - off) : 0;
    unsigned short* abuf = (unsigned short*)(ws + off);

    int ch2 = (int)(rem / ((size_t)Kp2 * 2));
    int ch3 = (int)(rem / ((size_t)Kp3 * 2));
    if (ch2 > N) ch2 = N;
    if (ch3 > N) ch3 = N;
    if (ch2 < 1) ch2 = 1;
    if (ch3 < 1) ch3 = 1;

    int egrid = (E + 255) / 256;

    // CSR + sorted edge metadata
    zero_kernel<<<(2 * N + 255) / 256, 256, 0, stream>>>(counts, 2 * N);
    count_kernel<<<egrid, 256, 0, stream>>>(ei, counts);
    scan_kernel<<<1, 256, 0, stream>>>(counts, row_start);
    fill_kernel<<<egrid, 256, 0, stream>>>(ei, row_start, cursor, slot_pos);
    edge_prep_sorted<<<egrid, 256, 0, stream>>>(pseudo, ei, slot_pos, srcs, bas8, kidb);

    // pack weights (bf16 MFMA B-fragment order)
    int tot2 = (Kp2 / 32) * (64 / 16) * 64;
    int tot3 = (Kp3 / 32) * (128 / 16) * 64;
    pack_w_kernel<<<(tot2 + 255) / 256, 256, 0, stream>>>(W2, root2, KTOT * 32, 64, tot2, Wp2);
    pack_w_kernel<<<(tot3 + 255) / 256, 256, 0, stream>>>(W3, root3, KTOT * 64, 128, tot3, Wp3);

    // layer 1 (fp32 path, cheap)
    layer1_acc_kernel<<<(N + 3) / 4, 256, 0, stream>>>(srcs, bas8, kidb, row_start, x, acc1);
    dense1_kernel<<<(N + 7) / 8, 256, 0, stream>>>(acc1, x, W1, root1, b1, h1);

    // layer 2 (CIN=32): accumulate -> bf16 A rows -> MFMA GEMM (NN=64)
    for (int n0 = 0; n0 < N; n0 += ch2) {
        int mc = N - n0 < ch2 ? N - n0 : ch2;
        accumulate_kernel<32><<<(mc + 3) / 4, 256, 0, stream>>>(
            srcs, bas8, kidb, row_start, h1, abuf, n0, mc);
        mfma_gemm<4><<<(mc + 63) / 64, 256, 0, stream>>>(abuf, Wp2, b2, h2, Kp2, n0, mc);
    }

    // layer 3 (CIN=64): NN=128, logits to d_out
    for (int n0 = 0; n0 < N; n0 += ch3) {
        int mc = N - n0 < ch3 ? N - n0 : ch3;
        accumulate_kernel<64><<<(mc + 3) / 4, 256, 0, stream>>>(
            srcs, bas8, kidb, row_start, h2, abuf, n0, mc);
        mfma_gemm<8><<<(mc + 63) / 64, 256, 0, stream>>>(abuf, Wp3, b3, out, Kp3, n0, mc);
    }

    logsoftmax_kernel<<<N, 64, 0, stream>>>(out);
}

// Round 5
// 554.991 us; speedup vs baseline: 6.5675x; 1.3156x over previous
//
#include <hip/hip_runtime.h>
#include <hip/hip_bf16.h>

#define NN_NODES 20000
#define NE_EDGES 500000
#define KTOT 48

typedef __bf16 bf16x8 __attribute__((ext_vector_type(8)));
typedef float f32x4 __attribute__((ext_vector_type(4)));

__device__ inline unsigned short bf16_rne(float x) {
    unsigned int u = __float_as_uint(x);
    u = (u + 0x7fffu + ((u >> 16) & 1u)) >> 16;
    return (unsigned short)u;
}
__device__ inline unsigned int pack_bf16x2(float a, float b) {
    return (unsigned int)bf16_rne(a) | ((unsigned int)bf16_rne(b) << 16);
}

// ---------------------------------------------------------------------------
// Zero helper
// ---------------------------------------------------------------------------
__global__ void zero_kernel(int* __restrict__ p, int n) {
    int i = blockIdx.x * 256 + threadIdx.x;
    if (i < n) p[i] = 0;
}

// ---------------------------------------------------------------------------
// CSR build
// ---------------------------------------------------------------------------
__global__ void count_kernel(const int* __restrict__ ei, int* __restrict__ counts) {
    int e = blockIdx.x * 256 + threadIdx.x;
    if (e < NE_EDGES) atomicAdd(&counts[ei[NE_EDGES + e]], 1);
}

__global__ void scan_kernel(const int* __restrict__ counts, int* __restrict__ row_start) {
    __shared__ int part[256];
    const int CH = (NN_NODES + 255) / 256;
    int t = threadIdx.x;
    int begin = t * CH;
    int end = begin + CH;
    if (end > NN_NODES) end = NN_NODES;
    int sum = 0;
    for (int i = begin; i < end && i < NN_NODES; ++i) sum += counts[i];
    part[t] = sum;
    __syncthreads();
    for (int off = 1; off < 256; off <<= 1) {
        int v = (t >= off) ? part[t - off] : 0;
        __syncthreads();
        part[t] += v;
        __syncthreads();
    }
    int run = (t == 0) ? 0 : part[t - 1];
    for (int i = begin; i < end && i < NN_NODES; ++i) {
        row_start[i] = run;
        run += counts[i];
    }
    if (t == 255) row_start[NN_NODES] = part[255];
}

__global__ void fill_kernel(const int* __restrict__ ei, const int* __restrict__ row_start,
                            int* __restrict__ cursor, int* __restrict__ slot_pos) {
    int e = blockIdx.x * 256 + threadIdx.x;
    if (e < NE_EDGES) {
        int d = ei[NE_EDGES + e];
        int p = atomicAdd(&cursor[d], 1);
        slot_pos[e] = row_start[d] + p;
    }
}

// ---------------------------------------------------------------------------
// Edge prep (CSR slot order). All 8 kidx of an edge pairwise DISTINCT
// (clamped zero-weight corners redirected) => non-atomic LDS RMW is safe.
// ---------------------------------------------------------------------------
__global__ void edge_prep_sorted(const float* __restrict__ pseudo, const int* __restrict__ ei,
                                 const int* __restrict__ slot_pos,
                                 int* __restrict__ srcs,
                                 float* __restrict__ bas8, unsigned char* __restrict__ kidb) {
    int e = blockIdx.x * 256 + threadIdx.x;
    if (e >= NE_EDGES) return;
    const int ksa[3] = {3, 8, 2};
    float frac[3];
    int id_lo[3], id_hi[3];
#pragma unroll
    for (int d = 0; d < 3; ++d) {
        float u = pseudo[e * 3 + d] * (1.0f / 4.5f);
        u = fminf(fmaxf(u, 0.0f), 1.0f);
        float pos = u * (float)(ksa[d] - 1);
        float fl = floorf(pos);
        int lo = (int)fl;
        frac[d] = pos - fl;
        id_lo[d] = lo;
        id_hi[d] = (lo + 1 <= ksa[d] - 1) ? lo + 1 : lo - 1;
    }
    int j = slot_pos[e];
    srcs[j] = ei[e];
#pragma unroll
    for (int s = 0; s < 8; ++s) {
        float w = 1.0f;
        int k = 0;
        const int strides[3] = {16, 2, 1};
#pragma unroll
        for (int d = 0; d < 3; ++d) {
            int bit = (s >> d) & 1;
            k += (bit ? id_hi[d] : id_lo[d]) * strides[d];
            w *= bit ? frac[d] : (1.0f - frac[d]);
        }
        bas8[(size_t)j * 8 + s] = w;
        kidb[(size_t)j * 8 + s] = (unsigned char)k;
    }
}

// ---------------------------------------------------------------------------
// Layer 1 FUSED (c_in = 1): wave per node, 8 edges x 8 splines in parallel
// across the 64 lanes. Non-atomic LDS RMW into 8 per-edge-sub copies
// (edge-subs distinct + within-edge k's distinct => race-free). Reduce the
// 8 copies, then apply W1/root1/b1 + relu in the same kernel (W1 in LDS).
// ---------------------------------------------------------------------------
__global__ __launch_bounds__(256) void layer1_fused_kernel(
    const int* __restrict__ srcs, const float* __restrict__ bas8,
    const unsigned char* __restrict__ kidb, const int* __restrict__ row_start,
    const float* __restrict__ x, const float* __restrict__ W1,
    const float* __restrict__ root1, const float* __restrict__ b1,
    float* __restrict__ h1) {
    __shared__ float w1s[KTOT * 32];      // 6 KB
    __shared__ float scopy[4][8 * 49];    // 4 waves x 8 copies x 48(+1 pad)
    int tid = threadIdx.x;
    for (int l = tid; l < KTOT * 32; l += 256) w1s[l] = W1[l];
    int w = tid >> 6, lane = tid & 63;
    int n = blockIdx.x * 4 + w;
    bool act = n < NN_NODES;
    float* sc = &scopy[w][0];
    for (int l = lane; l < 8 * 49; l += 64) sc[l] = 0.0f;
    if (act) {
        int beg = row_start[n], end = row_start[n + 1];
        int es = lane >> 3;   // edge sub-slot 0..7
        int sp = lane & 7;    // spline 0..7
        for (int jb = beg; jb < end; jb += 8) {
            int j = jb + es;
            if (j < end) {
                float b = bas8[(size_t)jb * 8 + lane];   // == bas8[j*8+sp], coalesced
                int k = kidb[(size_t)jb * 8 + lane];
                float xv = x[srcs[j]];
                sc[es * 49 + k] += b * xv;               // race-free (see above)
            }
        }
        // reduce 8 copies -> sc[0..47]  (wave-internal, DS ops are in order)
        if (lane < KTOT) {
            float a = 0.0f;
#pragma unroll
            for (int e = 0; e < 8; ++e) a += sc[e * 49 + lane];
            sc[lane] = a;
        }
    }
    __syncthreads();  // for w1s (and uniform: all threads reach)
    if (act && lane < 32) {
        float s = b1[lane] + x[n] * root1[lane];
#pragma unroll 8
        for (int k = 0; k < KTOT; ++k) s = fmaf(sc[k], w1s[k * 32 + lane], s);
        h1[n * 32 + lane] = fmaxf(s, 0.0f);
    }
}

// ---------------------------------------------------------------------------
// Accumulate (layers 2/3): wave per node, non-atomic LDS RMW; stores the
// A-row in BF16: [acc(KTOT*CIN) | h_prev(CIN)] -> Kp = 49*CIN bf16 per node.
// ---------------------------------------------------------------------------
template <int CIN>
__global__ __launch_bounds__(256) void accumulate_kernel(
    const int* __restrict__ srcs, const float* __restrict__ bas8,
    const unsigned char* __restrict__ kidb, const int* __restrict__ row_start,
    const float* __restrict__ h, unsigned short* __restrict__ abuf, int n0, int mc) {
    constexpr int ACC = KTOT * CIN;
    constexpr int KP = ACC + CIN;
    constexpr int LPS = CIN / 4;
    constexpr int NGRP = 64 / LPS;
    constexpr int SPL = 8 / NGRP;
    __shared__ float sacc[4 * ACC];
    int w = threadIdx.x >> 6, lane = threadIdx.x & 63;
    int n_local = blockIdx.x * 4 + w;
    if (n_local >= mc) return;
    int n = n0 + n_local;
    float4* s_node = (float4*)(sacc + w * ACC);
    for (int l = lane; l < ACC / 4; l += 64) s_node[l] = make_float4(0.f, 0.f, 0.f, 0.f);
    int chq = lane % LPS;
    int sg = lane / LPS;
    int beg = row_start[n], end = row_start[n + 1];
    int j = beg;
    float4 hv = make_float4(0.f, 0.f, 0.f, 0.f);
    if (j < end) {
        int s0 = srcs[j];
        hv = *(const float4*)&h[(size_t)s0 * CIN + chq * 4];
    }
    for (; j < end; ++j) {
        float4 hc = hv;
        int j1 = j + 1;
        if (j1 < end) {
            int s1 = srcs[j1];
            hv = *(const float4*)&h[(size_t)s1 * CIN + chq * 4];
        }
        const float* bp = bas8 + (size_t)j * 8;
        const unsigned char* kp = kidb + (size_t)j * 8;
        float bs[SPL];
        int ks[SPL];
        float4 ov[SPL];
#pragma unroll
        for (int t = 0; t < SPL; ++t) {
            int s = sg + t * NGRP;
            bs[t] = bp[s];
            ks[t] = kp[s];
        }
#pragma unroll
        for (int t = 0; t < SPL; ++t) ov[t] = s_node[ks[t] * LPS + chq];
#pragma unroll
        for (int t = 0; t < SPL; ++t) {
            float b = bs[t];
            ov[t].x = fmaf(b, hc.x, ov[t].x);
            ov[t].y = fmaf(b, hc.y, ov[t].y);
            ov[t].z = fmaf(b, hc.z, ov[t].z);
            ov[t].w = fmaf(b, hc.w, ov[t].w);
            s_node[ks[t] * LPS + chq] = ov[t];
        }
    }
    // store bf16 row: acc part then h_prev tail
    unsigned int* dstp = (unsigned int*)abuf + (size_t)n_local * (KP / 2);
    const float2* s2 = (const float2*)s_node;
    for (int l = lane; l < ACC / 2; l += 64) {
        float2 v = s2[l];
        dstp[l] = pack_bf16x2(v.x, v.y);
    }
    const float2* hrow = (const float2*)(h + (size_t)n * CIN);
    if (lane < CIN / 2) {
        float2 v = hrow[lane];
        dstp[ACC / 2 + lane] = pack_bf16x2(v.x, v.y);
    }
}

// ---------------------------------------------------------------------------
// Pack W' = [W(KK rows); root(CP rows)] (fp32, row-major [Kp][NN]) into MFMA
// B-fragment order: elem((t,c,l,j)) = W'[t*32 + (l>>4)*8 + j][c*16 + (l&15)].
// ---------------------------------------------------------------------------
__global__ void pack_w_kernel(const float* __restrict__ W, const float* __restrict__ root,
                              int KK, int NN, int total, unsigned short* __restrict__ Wp) {
    int tid = blockIdx.x * 256 + threadIdx.x;
    if (tid >= total) return;
    int nct = NN >> 4;
    int l = tid & 63;
    int c = (tid >> 6) % nct;
    int t = tid / (64 * nct);
    int n = c * 16 + (l & 15);
    int kbase = t * 32 + ((l >> 4) << 3);
    unsigned short vals[8];
#pragma unroll
    for (int jj = 0; jj < 8; ++jj) {
        int k = kbase + jj;
        float v = (k < KK) ? W[(size_t)k * NN + n] : root[(size_t)(k - KK) * NN + n];
        vals[jj] = bf16_rne(v);
    }
    *(uint4*)&Wp[(size_t)tid * 8] = *(uint4*)vals;
}

// ---------------------------------------------------------------------------
// MFMA GEMM: out[n0+r, :NN] = relu( Arow[r,:Kp](bf16) @ W'[Kp,NN] + bias ).
// ---------------------------------------------------------------------------
template <int NCT>
__global__ __launch_bounds__(256) void mfma_gemm(
    const unsigned short* __restrict__ A, const unsigned short* __restrict__ Wp,
    const float* __restrict__ bias, float* __restrict__ out,
    int Kp, int n0, int mc) {
    constexpr int NN = NCT * 16;
    int w = threadIdx.x >> 6, lane = threadIdx.x & 63;
    int row_local = blockIdx.x * 64 + w * 16 + (lane & 15);
    int row_c = min(row_local, mc - 1);
    const unsigned short* arow = A + (size_t)row_c * Kp + ((lane >> 4) << 3);
    const uint4* wpq = (const uint4*)Wp;
    f32x4 acc[NCT] = {};
    int tsteps = Kp >> 5;
    for (int t = 0; t < tsteps; ++t) {
        uint4 araw = *(const uint4*)(arow + t * 32);
        bf16x8 af = __builtin_bit_cast(bf16x8, araw);
        const uint4* bbase = wpq + ((size_t)t * NCT) * 64 + lane;
#pragma unroll
        for (int c = 0; c < NCT; ++c) {
            uint4 braw = bbase[c * 64];
            bf16x8 bfr = __builtin_bit_cast(bf16x8, braw);
            acc[c] = __builtin_amdgcn_mfma_f32_16x16x32_bf16(af, bfr, acc[c], 0, 0, 0);
        }
    }
    int col0 = lane & 15;
    int rbase = blockIdx.x * 64 + w * 16 + ((lane >> 4) << 2);
#pragma unroll
    for (int c = 0; c < NCT; ++c) {
        int col = c * 16 + col0;
        float bv = bias[col];
#pragma unroll
        for (int r = 0; r < 4; ++r) {
            int rowo = rbase + r;
            if (rowo < mc)
                out[(size_t)(n0 + rowo) * NN + col] = fmaxf(acc[c][r] + bv, 0.0f);
        }
    }
}

// ---------------------------------------------------------------------------
// log_softmax over rows of out[N,128], in place. One wave per row.
// ---------------------------------------------------------------------------
__global__ void logsoftmax_kernel(float* __restrict__ out) {
    int n = blockIdx.x;
    int lane = threadIdx.x;
    float v0 = out[(size_t)n * 128 + lane];
    float v1 = out[(size_t)n * 128 + 64 + lane];
    float m = fmaxf(v0, v1);
#pragma unroll
    for (int off = 32; off > 0; off >>= 1) m = fmaxf(m, __shfl_xor(m, off));
    float s = expf(v0 - m) + expf(v1 - m);
#pragma unroll
    for (int off = 32; off > 0; off >>= 1) s += __shfl_xor(s, off);
    float lse = m + logf(s);
    out[(size_t)n * 128 + lane] = v0 - lse;
    out[(size_t)n * 128 + 64 + lane] = v1 - lse;
}

// ---------------------------------------------------------------------------
// Launch
// ---------------------------------------------------------------------------
extern "C" void kernel_launch(void* const* d_in, const int* in_sizes, int n_in,
                              void* d_out, int out_size, void* d_ws, size_t ws_size,
                              hipStream_t stream) {
    const float* x = (const float*)d_in[0];
    const int* ei = (const int*)d_in[1];
    const float* pseudo = (const float*)d_in[2];
    const float* W1 = (const float*)d_in[3];
    const float* root1 = (const float*)d_in[4];
    const float* b1 = (const float*)d_in[5];
    const float* W2 = (const float*)d_in[6];
    const float* root2 = (const float*)d_in[7];
    const float* b2 = (const float*)d_in[8];
    const float* W3 = (const float*)d_in[9];
    const float* root3 = (const float*)d_in[10];
    const float* b3 = (const float*)d_in[11];
    float* out = (float*)d_out;
    char* ws = (char*)d_ws;

    const int N = NN_NODES, E = NE_EDGES;
    const int Kp2 = 49 * 32;   // 1568
    const int Kp3 = 49 * 64;   // 3136
    size_t off = 0;
    auto carve = [&](size_t bytes) {
        size_t p = off;
        off += (bytes + 255) & ~(size_t)255;
        return p;
    };
    int* counts = (int*)(ws + carve((size_t)N * 4 * 2));
    int* cursor = counts + N;
    int* row_start = (int*)(ws + carve((size_t)(N + 1) * 4));
    int* slot_pos = (int*)(ws + carve((size_t)E * 4));
    int* srcs = (int*)(ws + carve((size_t)E * 4));
    float* bas8 = (float*)(ws + carve((size_t)E * 8 * 4));
    unsigned char* kidb = (unsigned char*)(ws + carve((size_t)E * 8));
    float* h1 = (float*)(ws + carve((size_t)N * 32 * 4));
    float* h2 = (float*)(ws + carve((size_t)N * 64 * 4));
    unsigned short* Wp2 = (unsigned short*)(ws + carve((size_t)Kp2 * 64 * 2));
    unsigned short* Wp3 = (unsigned short*)(ws + carve((size_t)Kp3 * 128 * 2));
    size_t rem = (ws_size > off) ? (ws_size - off) : 0;
    unsigned short* abuf = (unsigned short*)(ws + off);

    int ch2 = (int)(rem / ((size_t)Kp2 * 2));
    int ch3 = (int)(rem / ((size_t)Kp3 * 2));
    if (ch2 > N) ch2 = N;
    if (ch3 > N) ch3 = N;
    if (ch2 < 1) ch2 = 1;
    if (ch3 < 1) ch3 = 1;

    int egrid = (E + 255) / 256;

    // CSR + sorted edge metadata
    zero_kernel<<<(2 * N + 255) / 256, 256, 0, stream>>>(counts, 2 * N);
    count_kernel<<<egrid, 256, 0, stream>>>(ei, counts);
    scan_kernel<<<1, 256, 0, stream>>>(counts, row_start);
    fill_kernel<<<egrid, 256, 0, stream>>>(ei, row_start, cursor, slot_pos);
    edge_prep_sorted<<<egrid, 256, 0, stream>>>(pseudo, ei, slot_pos, srcs, bas8, kidb);

    // pack weights (bf16 MFMA B-fragment order)
    int tot2 = (Kp2 / 32) * (64 / 16) * 64;
    int tot3 = (Kp3 / 32) * (128 / 16) * 64;
    pack_w_kernel<<<(tot2 + 255) / 256, 256, 0, stream>>>(W2, root2, KTOT * 32, 64, tot2, Wp2);
    pack_w_kernel<<<(tot3 + 255) / 256, 256, 0, stream>>>(W3, root3, KTOT * 64, 128, tot3, Wp3);

    // layer 1 (fused accumulate + dense + relu)
    layer1_fused_kernel<<<(N + 3) / 4, 256, 0, stream>>>(srcs, bas8, kidb, row_start, x,
                                                         W1, root1, b1, h1);

    // layer 2 (CIN=32): accumulate -> bf16 A rows -> MFMA GEMM (NN=64)
    for (int n0 = 0; n0 < N; n0 += ch2) {
        int mc = N - n0 < ch2 ? N - n0 : ch2;
        accumulate_kernel<32><<<(mc + 3) / 4, 256, 0, stream>>>(
            srcs, bas8, kidb, row_start, h1, abuf, n0, mc);
        mfma_gemm<4><<<(mc + 63) / 64, 256, 0, stream>>>(abuf, Wp2, b2, h2, Kp2, n0, mc);
    }

    // layer 3 (CIN=64): NN=128, logits to d_out
    for (int n0 = 0; n0 < N; n0 += ch3) {
        int mc = N - n0 < ch3 ? N - n0 : ch3;
        accumulate_kernel<64><<<(mc + 3) / 4, 256, 0, stream>>>(
            srcs, bas8, kidb, row_start, h2, abuf, n0, mc);
        mfma_gemm<8><<<(mc + 63) / 64, 256, 0, stream>>>(abuf, Wp3, b3, out, Kp3, n0, mc);
    }

    logsoftmax_kernel<<<N, 64, 0, stream>>>(out);
}

// Round 6
// 524.843 us; speedup vs baseline: 6.9448x; 1.0574x over previous
//
#include <hip/hip_runtime.h>
#include <hip/hip_bf16.h>

#define NN_NODES 20000
#define NE_EDGES 500000
#define KTOT 48

typedef __bf16 bf16x8 __attribute__((ext_vector_type(8)));
typedef float f32x4 __attribute__((ext_vector_type(4)));

__device__ inline unsigned short bf16_rne(float x) {
    unsigned int u = __float_as_uint(x);
    u = (u + 0x7fffu + ((u >> 16) & 1u)) >> 16;
    return (unsigned short)u;
}
__device__ inline unsigned int pack_bf16x2(float a, float b) {
    return (unsigned int)bf16_rne(a) | ((unsigned int)bf16_rne(b) << 16);
}

// ---------------------------------------------------------------------------
// Zero helper
// ---------------------------------------------------------------------------
__global__ void zero_kernel(int* __restrict__ p, int n) {
    int i = blockIdx.x * 256 + threadIdx.x;
    if (i < n) p[i] = 0;
}

// ---------------------------------------------------------------------------
// CSR build
// ---------------------------------------------------------------------------
__global__ void count_kernel(const int* __restrict__ ei, int* __restrict__ counts) {
    int e = blockIdx.x * 256 + threadIdx.x;
    if (e < NE_EDGES) atomicAdd(&counts[ei[NE_EDGES + e]], 1);
}

__global__ void scan_kernel(const int* __restrict__ counts, int* __restrict__ row_start) {
    __shared__ int part[256];
    const int CH = (NN_NODES + 255) / 256;
    int t = threadIdx.x;
    int begin = t * CH;
    int end = begin + CH;
    if (end > NN_NODES) end = NN_NODES;
    int sum = 0;
    for (int i = begin; i < end && i < NN_NODES; ++i) sum += counts[i];
    part[t] = sum;
    __syncthreads();
    for (int off = 1; off < 256; off <<= 1) {
        int v = (t >= off) ? part[t - off] : 0;
        __syncthreads();
        part[t] += v;
        __syncthreads();
    }
    int run = (t == 0) ? 0 : part[t - 1];
    for (int i = begin; i < end && i < NN_NODES; ++i) {
        row_start[i] = run;
        run += counts[i];
    }
    if (t == 255) row_start[NN_NODES] = part[255];
}

__global__ void fill_kernel(const int* __restrict__ ei, const int* __restrict__ row_start,
                            int* __restrict__ cursor, int* __restrict__ slot_pos) {
    int e = blockIdx.x * 256 + threadIdx.x;
    if (e < NE_EDGES) {
        int d = ei[NE_EDGES + e];
        int p = atomicAdd(&cursor[d], 1);
        slot_pos[e] = row_start[d] + p;
    }
}

// ---------------------------------------------------------------------------
// Edge prep (CSR slot order). All 8 kidx of an edge pairwise DISTINCT
// (clamped zero-weight corners redirected) => non-atomic LDS RMW is safe.
// ---------------------------------------------------------------------------
__global__ void edge_prep_sorted(const float* __restrict__ pseudo, const int* __restrict__ ei,
                                 const int* __restrict__ slot_pos,
                                 int* __restrict__ srcs,
                                 float* __restrict__ bas8, unsigned char* __restrict__ kidb) {
    int e = blockIdx.x * 256 + threadIdx.x;
    if (e >= NE_EDGES) return;
    const int ksa[3] = {3, 8, 2};
    float frac[3];
    int id_lo[3], id_hi[3];
#pragma unroll
    for (int d = 0; d < 3; ++d) {
        float u = pseudo[e * 3 + d] * (1.0f / 4.5f);
        u = fminf(fmaxf(u, 0.0f), 1.0f);
        float pos = u * (float)(ksa[d] - 1);
        float fl = floorf(pos);
        int lo = (int)fl;
        frac[d] = pos - fl;
        id_lo[d] = lo;
        id_hi[d] = (lo + 1 <= ksa[d] - 1) ? lo + 1 : lo - 1;
    }
    int j = slot_pos[e];
    srcs[j] = ei[e];
#pragma unroll
    for (int s = 0; s < 8; ++s) {
        float w = 1.0f;
        int k = 0;
        const int strides[3] = {16, 2, 1};
#pragma unroll
        for (int d = 0; d < 3; ++d) {
            int bit = (s >> d) & 1;
            k += (bit ? id_hi[d] : id_lo[d]) * strides[d];
            w *= bit ? frac[d] : (1.0f - frac[d]);
        }
        bas8[(size_t)j * 8 + s] = w;
        kidb[(size_t)j * 8 + s] = (unsigned char)k;
    }
}

// ---------------------------------------------------------------------------
// Layer 1 FUSED (c_in = 1): wave per node, 8 edges x 8 splines in parallel.
// ---------------------------------------------------------------------------
__global__ __launch_bounds__(256) void layer1_fused_kernel(
    const int* __restrict__ srcs, const float* __restrict__ bas8,
    const unsigned char* __restrict__ kidb, const int* __restrict__ row_start,
    const float* __restrict__ x, const float* __restrict__ W1,
    const float* __restrict__ root1, const float* __restrict__ b1,
    float* __restrict__ h1) {
    __shared__ float w1s[KTOT * 32];
    __shared__ float scopy[4][8 * 49];
    int tid = threadIdx.x;
    for (int l = tid; l < KTOT * 32; l += 256) w1s[l] = W1[l];
    int w = tid >> 6, lane = tid & 63;
    int n = blockIdx.x * 4 + w;
    bool act = n < NN_NODES;
    float* sc = &scopy[w][0];
    for (int l = lane; l < 8 * 49; l += 64) sc[l] = 0.0f;
    if (act) {
        int beg = row_start[n], end = row_start[n + 1];
        int es = lane >> 3;
        for (int jb = beg; jb < end; jb += 8) {
            int j = jb + es;
            if (j < end) {
                float b = bas8[(size_t)jb * 8 + lane];
                int k = kidb[(size_t)jb * 8 + lane];
                float xv = x[srcs[j]];
                sc[es * 49 + k] += b * xv;
            }
        }
        if (lane < KTOT) {
            float a = 0.0f;
#pragma unroll
            for (int e = 0; e < 8; ++e) a += sc[e * 49 + lane];
            sc[lane] = a;
        }
    }
    __syncthreads();
    if (act && lane < 32) {
        float s = b1[lane] + x[n] * root1[lane];
#pragma unroll 8
        for (int k = 0; k < KTOT; ++k) s = fmaf(sc[k], w1s[k * 32 + lane], s);
        h1[n * 32 + lane] = fmaxf(s, 0.0f);
    }
}

// ---------------------------------------------------------------------------
// Accumulate (layers 2/3): WSPN waves per node, each wave owns a 32-channel
// half (CH=32). SPL=1: per edge exactly one ds_read_b128 + fma + one
// ds_write_b128. Wave-private channel ranges => no sync, no atomics.
// LDS/block = 24 KB for both configs -> 6 blocks/CU.
// Output row in BF16: [acc(KTOT*CIN) | h_prev(CIN)] -> Kp = 49*CIN.
// ---------------------------------------------------------------------------
template <int CIN, int WSPN>
__global__ __launch_bounds__(256) void accumulate_kernel(
    const int* __restrict__ srcs, const float* __restrict__ bas8,
    const unsigned char* __restrict__ kidb, const int* __restrict__ row_start,
    const float* __restrict__ h, unsigned short* __restrict__ abuf, int n0, int mc) {
    constexpr int ACC = KTOT * CIN;        // floats per node
    constexpr int NPB = 4 / WSPN;          // nodes per 256-thread block
    static_assert(CIN / WSPN == 32, "each wave owns 32 channels");
    __shared__ float sacc[NPB * ACC];
    int w = threadIdx.x >> 6, lane = threadIdx.x & 63;
    int nl = w / WSPN;                     // node slot in block
    int sub = w % WSPN;                    // which channel half
    int n_local = blockIdx.x * NPB + nl;
    if (n_local >= mc) return;
    int n = n0 + n_local;
    float* s_node = sacc + nl * ACC;
    int cb = sub * 32;                     // channel base for this wave
    int chq = lane & 7;                    // float4 slot within 32 channels
    int sg = lane >> 3;                    // spline group 0..7
    // zero this wave's half
    for (int l = lane; l < KTOT * 8; l += 64) {
        int k = l >> 3, c4 = l & 7;
        *(float4*)&s_node[k * CIN + cb + c4 * 4] = make_float4(0.f, 0.f, 0.f, 0.f);
    }
    int beg = row_start[n], end = row_start[n + 1];
    int j = beg;
    float4 hv = make_float4(0.f, 0.f, 0.f, 0.f);
    float bv = 0.0f;
    int kv = 0;
    if (j < end) {
        hv = *(const float4*)&h[(size_t)srcs[j] * CIN + cb + chq * 4];
        bv = bas8[(size_t)j * 8 + sg];
        kv = kidb[(size_t)j * 8 + sg];
    }
    for (; j < end; ++j) {
        float4 hc = hv;
        float bc = bv;
        int kc = kv;
        int j1 = j + 1;
        if (j1 < end) {
            hv = *(const float4*)&h[(size_t)srcs[j1] * CIN + cb + chq * 4];
            bv = bas8[(size_t)j1 * 8 + sg];
            kv = kidb[(size_t)j1 * 8 + sg];
        }
        float4* slot = (float4*)&s_node[kc * CIN + cb + chq * 4];
        float4 ov = *slot;
        ov.x = fmaf(bc, hc.x, ov.x);
        ov.y = fmaf(bc, hc.y, ov.y);
        ov.z = fmaf(bc, hc.z, ov.z);
        ov.w = fmaf(bc, hc.w, ov.w);
        *slot = ov;
    }
    // store this wave's half as bf16 (pairs)
    unsigned int* dstp = (unsigned int*)abuf + (size_t)n_local * ((ACC + CIN) / 2);
    for (int l = lane; l < KTOT * 16; l += 64) {
        int k = l >> 4, cp = l & 15;
        const float2 v = *(const float2*)&s_node[k * CIN + cb + cp * 2];
        dstp[k * (CIN / 2) + (cb >> 1) + cp] = pack_bf16x2(v.x, v.y);
    }
    // h_prev tail (this wave's half)
    if (lane < 16) {
        const float2 v = *(const float2*)&h[(size_t)n * CIN + cb + lane * 2];
        dstp[ACC / 2 + (cb >> 1) + lane] = pack_bf16x2(v.x, v.y);
    }
}

// ---------------------------------------------------------------------------
// Pack W' = [W(KK rows); root(CP rows)] (fp32, row-major [Kp][NN]) into MFMA
// B-fragment order: elem((t,c,l,j)) = W'[t*32 + (l>>4)*8 + j][c*16 + (l&15)].
// ---------------------------------------------------------------------------
__global__ void pack_w_kernel(const float* __restrict__ W, const float* __restrict__ root,
                              int KK, int NN, int total, unsigned short* __restrict__ Wp) {
    int tid = blockIdx.x * 256 + threadIdx.x;
    if (tid >= total) return;
    int nct = NN >> 4;
    int l = tid & 63;
    int c = (tid >> 6) % nct;
    int t = tid / (64 * nct);
    int n = c * 16 + (l & 15);
    int kbase = t * 32 + ((l >> 4) << 3);
    unsigned short vals[8];
#pragma unroll
    for (int jj = 0; jj < 8; ++jj) {
        int k = kbase + jj;
        float v = (k < KK) ? W[(size_t)k * NN + n] : root[(size_t)(k - KK) * NN + n];
        vals[jj] = bf16_rne(v);
    }
    *(uint4*)&Wp[(size_t)tid * 8] = *(uint4*)vals;
}

// ---------------------------------------------------------------------------
// MFMA GEMM: out[n0+r, :NN] = relu( Arow[r,:Kp](bf16) @ W'[Kp,NN] + bias ).
// ---------------------------------------------------------------------------
template <int NCT>
__global__ __launch_bounds__(256) void mfma_gemm(
    const unsigned short* __restrict__ A, const unsigned short* __restrict__ Wp,
    const float* __restrict__ bias, float* __restrict__ out,
    int Kp, int n0, int mc) {
    constexpr int NN = NCT * 16;
    int w = threadIdx.x >> 6, lane = threadIdx.x & 63;
    int row_local = blockIdx.x * 64 + w * 16 + (lane & 15);
    int row_c = min(row_local, mc - 1);
    const unsigned short* arow = A + (size_t)row_c * Kp + ((lane >> 4) << 3);
    const uint4* wpq = (const uint4*)Wp;
    f32x4 acc[NCT] = {};
    int tsteps = Kp >> 5;
    for (int t = 0; t < tsteps; ++t) {
        uint4 araw = *(const uint4*)(arow + t * 32);
        bf16x8 af = __builtin_bit_cast(bf16x8, araw);
        const uint4* bbase = wpq + ((size_t)t * NCT) * 64 + lane;
#pragma unroll
        for (int c = 0; c < NCT; ++c) {
            uint4 braw = bbase[c * 64];
            bf16x8 bfr = __builtin_bit_cast(bf16x8, braw);
            acc[c] = __builtin_amdgcn_mfma_f32_16x16x32_bf16(af, bfr, acc[c], 0, 0, 0);
        }
    }
    int col0 = lane & 15;
    int rbase = blockIdx.x * 64 + w * 16 + ((lane >> 4) << 2);
#pragma unroll
    for (int c = 0; c < NCT; ++c) {
        int col = c * 16 + col0;
        float bv = bias[col];
#pragma unroll
        for (int r = 0; r < 4; ++r) {
            int rowo = rbase + r;
            if (rowo < mc)
                out[(size_t)(n0 + rowo) * NN + col] = fmaxf(acc[c][r] + bv, 0.0f);
        }
    }
}

// ---------------------------------------------------------------------------
// log_softmax over rows of out[N,128], in place. One wave per row.
// ---------------------------------------------------------------------------
__global__ void logsoftmax_kernel(float* __restrict__ out) {
    int n = blockIdx.x;
    int lane = threadIdx.x;
    float v0 = out[(size_t)n * 128 + lane];
    float v1 = out[(size_t)n * 128 + 64 + lane];
    float m = fmaxf(v0, v1);
#pragma unroll
    for (int off = 32; off > 0; off >>= 1) m = fmaxf(m, __shfl_xor(m, off));
    float s = expf(v0 - m) + expf(v1 - m);
#pragma unroll
    for (int off = 32; off > 0; off >>= 1) s += __shfl_xor(s, off);
    float lse = m + logf(s);
    out[(size_t)n * 128 + lane] = v0 - lse;
    out[(size_t)n * 128 + 64 + lane] = v1 - lse;
}

// ---------------------------------------------------------------------------
// Launch
// ---------------------------------------------------------------------------
extern "C" void kernel_launch(void* const* d_in, const int* in_sizes, int n_in,
                              void* d_out, int out_size, void* d_ws, size_t ws_size,
                              hipStream_t stream) {
    const float* x = (const float*)d_in[0];
    const int* ei = (const int*)d_in[1];
    const float* pseudo = (const float*)d_in[2];
    const float* W1 = (const float*)d_in[3];
    const float* root1 = (const float*)d_in[4];
    const float* b1 = (const float*)d_in[5];
    const float* W2 = (const float*)d_in[6];
    const float* root2 = (const float*)d_in[7];
    const float* b2 = (const float*)d_in[8];
    const float* W3 = (const float*)d_in[9];
    const float* root3 = (const float*)d_in[10];
    const float* b3 = (const float*)d_in[11];
    float* out = (float*)d_out;
    char* ws = (char*)d_ws;

    const int N = NN_NODES, E = NE_EDGES;
    const int Kp2 = 49 * 32;   // 1568
    const int Kp3 = 49 * 64;   // 3136
    size_t off = 0;
    auto carve = [&](size_t bytes) {
        size_t p = off;
        off += (bytes + 255) & ~(size_t)255;
        return p;
    };
    int* counts = (int*)(ws + carve((size_t)N * 4 * 2));
    int* cursor = counts + N;
    int* row_start = (int*)(ws + carve((size_t)(N + 1) * 4));
    int* slot_pos = (int*)(ws + carve((size_t)E * 4));
    int* srcs = (int*)(ws + carve((size_t)E * 4));
    float* bas8 = (float*)(ws + carve((size_t)E * 8 * 4));
    unsigned char* kidb = (unsigned char*)(ws + carve((size_t)E * 8));
    float* h1 = (float*)(ws + carve((size_t)N * 32 * 4));
    float* h2 = (float*)(ws + carve((size_t)N * 64 * 4));
    unsigned short* Wp2 = (unsigned short*)(ws + carve((size_t)Kp2 * 64 * 2));
    unsigned short* Wp3 = (unsigned short*)(ws + carve((size_t)Kp3 * 128 * 2));
    size_t rem = (ws_size > off) ? (ws_size - off) : 0;
    unsigned short* abuf = (unsigned short*)(ws + off);

    int ch2 = (int)(rem / ((size_t)Kp2 * 2));
    int ch3 = (int)(rem / ((size_t)Kp3 * 2));
    if (ch2 > N) ch2 = N;
    if (ch3 > N) ch3 = N;
    if (ch2 < 1) ch2 = 1;
    if (ch3 < 1) ch3 = 1;

    int egrid = (E + 255) / 256;

    // CSR + sorted edge metadata
    zero_kernel<<<(2 * N + 255) / 256, 256, 0, stream>>>(counts, 2 * N);
    count_kernel<<<egrid, 256, 0, stream>>>(ei, counts);
    scan_kernel<<<1, 256, 0, stream>>>(counts, row_start);
    fill_kernel<<<egrid, 256, 0, stream>>>(ei, row_start, cursor, slot_pos);
    edge_prep_sorted<<<egrid, 256, 0, stream>>>(pseudo, ei, slot_pos, srcs, bas8, kidb);

    // pack weights (bf16 MFMA B-fragment order)
    int tot2 = (Kp2 / 32) * (64 / 16) * 64;
    int tot3 = (Kp3 / 32) * (128 / 16) * 64;
    pack_w_kernel<<<(tot2 + 255) / 256, 256, 0, stream>>>(W2, root2, KTOT * 32, 64, tot2, Wp2);
    pack_w_kernel<<<(tot3 + 255) / 256, 256, 0, stream>>>(W3, root3, KTOT * 64, 128, tot3, Wp3);

    // layer 1 (fused accumulate + dense + relu)
    layer1_fused_kernel<<<(N + 3) / 4, 256, 0, stream>>>(srcs, bas8, kidb, row_start, x,
                                                         W1, root1, b1, h1);

    // layer 2 (CIN=32, 1 wave/node, 4 nodes/block)
    for (int n0 = 0; n0 < N; n0 += ch2) {
        int mc = N - n0 < ch2 ? N - n0 : ch2;
        accumulate_kernel<32, 1><<<(mc + 3) / 4, 256, 0, stream>>>(
            srcs, bas8, kidb, row_start, h1, abuf, n0, mc);
        mfma_gemm<4><<<(mc + 63) / 64, 256, 0, stream>>>(abuf, Wp2, b2, h2, Kp2, n0, mc);
    }

    // layer 3 (CIN=64, 2 waves/node, 2 nodes/block)
    for (int n0 = 0; n0 < N; n0 += ch3) {
        int mc = N - n0 < ch3 ? N - n0 : ch3;
        accumulate_kernel<64, 2><<<(mc + 1) / 2, 256, 0, stream>>>(
            srcs, bas8, kidb, row_start, h2, abuf, n0, mc);
        mfma_gemm<8><<<(mc + 63) / 64, 256, 0, stream>>>(abuf, Wp3, b3, out, Kp3, n0, mc);
    }

    logsoftmax_kernel<<<N, 64, 0, stream>>>(out);
}

// Round 8
// 421.190 us; speedup vs baseline: 8.6539x; 1.2461x over previous
//
#include <hip/hip_runtime.h>
#include <hip/hip_bf16.h>

#define NN_NODES 20000
#define NE_EDGES 500000
#define KTOT 48

typedef __bf16 bf16x8 __attribute__((ext_vector_type(8)));
typedef float f32x4 __attribute__((ext_vector_type(4)));

__device__ inline unsigned short bf16_rne(float x) {
    unsigned int u = __float_as_uint(x);
    u = (u + 0x7fffu + ((u >> 16) & 1u)) >> 16;
    return (unsigned short)u;
}
__device__ inline unsigned int pack_bf16x2(float a, float b) {
    return (unsigned int)bf16_rne(a) | ((unsigned int)bf16_rne(b) << 16);
}

// ---------------------------------------------------------------------------
// Zero helper
// ---------------------------------------------------------------------------
__global__ void zero_kernel(int* __restrict__ p, int n) {
    int i = blockIdx.x * 256 + threadIdx.x;
    if (i < n) p[i] = 0;
}

// ---------------------------------------------------------------------------
// CSR build
// ---------------------------------------------------------------------------
__global__ void count_kernel(const int* __restrict__ ei, int* __restrict__ counts) {
    int e = blockIdx.x * 256 + threadIdx.x;
    if (e < NE_EDGES) atomicAdd(&counts[ei[NE_EDGES + e]], 1);
}

__global__ void scan_kernel(const int* __restrict__ counts, int* __restrict__ row_start) {
    __shared__ int part[256];
    const int CH = (NN_NODES + 255) / 256;
    int t = threadIdx.x;
    int begin = t * CH;
    int end = begin + CH;
    if (end > NN_NODES) end = NN_NODES;
    int sum = 0;
    for (int i = begin; i < end && i < NN_NODES; ++i) sum += counts[i];
    part[t] = sum;
    __syncthreads();
    for (int off = 1; off < 256; off <<= 1) {
        int v = (t >= off) ? part[t - off] : 0;
        __syncthreads();
        part[t] += v;
        __syncthreads();
    }
    int run = (t == 0) ? 0 : part[t - 1];
    for (int i = begin; i < end && i < NN_NODES; ++i) {
        row_start[i] = run;
        run += counts[i];
    }
    if (t == 255) row_start[NN_NODES] = part[255];
}

__global__ void fill_kernel(const int* __restrict__ ei, const int* __restrict__ row_start,
                            int* __restrict__ cursor, int* __restrict__ slot_pos) {
    int e = blockIdx.x * 256 + threadIdx.x;
    if (e < NE_EDGES) {
        int d = ei[NE_EDGES + e];
        int p = atomicAdd(&cursor[d], 1);
        slot_pos[e] = row_start[d] + p;
    }
}

// ---------------------------------------------------------------------------
// Edge prep (CSR slot order). All 8 kidx of an edge pairwise DISTINCT
// (clamped zero-weight corners redirected) => non-atomic LDS writes/RMW safe.
// ---------------------------------------------------------------------------
__global__ void edge_prep_sorted(const float* __restrict__ pseudo, const int* __restrict__ ei,
                                 const int* __restrict__ slot_pos,
                                 int* __restrict__ srcs,
                                 float* __restrict__ bas8, unsigned char* __restrict__ kidb) {
    int e = blockIdx.x * 256 + threadIdx.x;
    if (e >= NE_EDGES) return;
    const int ksa[3] = {3, 8, 2};
    float frac[3];
    int id_lo[3], id_hi[3];
#pragma unroll
    for (int d = 0; d < 3; ++d) {
        float u = pseudo[e * 3 + d] * (1.0f / 4.5f);
        u = fminf(fmaxf(u, 0.0f), 1.0f);
        float pos = u * (float)(ksa[d] - 1);
        float fl = floorf(pos);
        int lo = (int)fl;
        frac[d] = pos - fl;
        id_lo[d] = lo;
        id_hi[d] = (lo + 1 <= ksa[d] - 1) ? lo + 1 : lo - 1;
    }
    int j = slot_pos[e];
    srcs[j] = ei[e];
#pragma unroll
    for (int s = 0; s < 8; ++s) {
        float w = 1.0f;
        int k = 0;
        const int strides[3] = {16, 2, 1};
#pragma unroll
        for (int d = 0; d < 3; ++d) {
            int bit = (s >> d) & 1;
            k += (bit ? id_hi[d] : id_lo[d]) * strides[d];
            w *= bit ? frac[d] : (1.0f - frac[d]);
        }
        bas8[(size_t)j * 8 + s] = w;
        kidb[(size_t)j * 8 + s] = (unsigned char)k;
    }
}

// ---------------------------------------------------------------------------
// Layer 1 FUSED (c_in = 1): wave per node, 8 edges x 8 splines in parallel.
// ---------------------------------------------------------------------------
__global__ __launch_bounds__(256) void layer1_fused_kernel(
    const int* __restrict__ srcs, const float* __restrict__ bas8,
    const unsigned char* __restrict__ kidb, const int* __restrict__ row_start,
    const float* __restrict__ x, const float* __restrict__ W1,
    const float* __restrict__ root1, const float* __restrict__ b1,
    float* __restrict__ h1) {
    __shared__ float w1s[KTOT * 32];
    __shared__ float scopy[4][8 * 49];
    int tid = threadIdx.x;
    for (int l = tid; l < KTOT * 32; l += 256) w1s[l] = W1[l];
    int w = tid >> 6, lane = tid & 63;
    int n = blockIdx.x * 4 + w;
    bool act = n < NN_NODES;
    float* sc = &scopy[w][0];
    for (int l = lane; l < 8 * 49; l += 64) sc[l] = 0.0f;
    if (act) {
        int beg = row_start[n], end = row_start[n + 1];
        int es = lane >> 3;
        for (int jb = beg; jb < end; jb += 8) {
            int j = jb + es;
            if (j < end) {
                float b = bas8[(size_t)jb * 8 + lane];
                int k = kidb[(size_t)jb * 8 + lane];
                float xv = x[srcs[j]];
                sc[es * 49 + k] += b * xv;
            }
        }
        if (lane < KTOT) {
            float a = 0.0f;
#pragma unroll
            for (int e = 0; e < 8; ++e) a += sc[e * 49 + lane];
            sc[lane] = a;
        }
    }
    __syncthreads();
    if (act && lane < 32) {
        float s = b1[lane] + x[n] * root1[lane];
#pragma unroll 8
        for (int k = 0; k < KTOT; ++k) s = fmaf(sc[k], w1s[k * 32 + lane], s);
        h1[n * 32 + lane] = fmaxf(s, 0.0f);
    }
}

// ---------------------------------------------------------------------------
// Layer-2 accumulate (ROUND-6 KNOWN-GOOD): 1 wave/node, CIN=32, one edge per
// iteration (read slot -> fma -> write slot; all wave addresses within an
// edge are distinct => safe). Emits bf16 row [acc(48*32) | h1(32)].
// ---------------------------------------------------------------------------
__global__ __launch_bounds__(256) void accumulate2_kernel(
    const int* __restrict__ srcs, const float* __restrict__ bas8,
    const unsigned char* __restrict__ kidb, const int* __restrict__ row_start,
    const float* __restrict__ h, unsigned short* __restrict__ abuf, int n0, int mc) {
    constexpr int CIN = 32;
    constexpr int ACC = KTOT * CIN;
    __shared__ float sacc[4 * ACC];
    int w = threadIdx.x >> 6, lane = threadIdx.x & 63;
    int n_local = blockIdx.x * 4 + w;
    if (n_local >= mc) return;
    int n = n0 + n_local;
    float* s_node = sacc + w * ACC;
    int chq = lane & 7;
    int sg = lane >> 3;
    int choff = chq * 4;
    for (int l = lane; l < KTOT * 8; l += 64) {
        int k = l >> 3, c4 = l & 7;
        *(float4*)&s_node[k * CIN + c4 * 4] = make_float4(0.f, 0.f, 0.f, 0.f);
    }
    int beg = row_start[n], end = row_start[n + 1];
    int j = beg;
    float4 hv = make_float4(0.f, 0.f, 0.f, 0.f);
    float bv = 0.0f;
    int kv = 0;
    if (j < end) {
        hv = *(const float4*)&h[(size_t)srcs[j] * CIN + choff];
        bv = bas8[(size_t)j * 8 + sg];
        kv = kidb[(size_t)j * 8 + sg];
    }
    for (; j < end; ++j) {
        float4 hc = hv;
        float bc = bv;
        int kc = kv;
        int j1 = j + 1;
        if (j1 < end) {
            hv = *(const float4*)&h[(size_t)srcs[j1] * CIN + choff];
            bv = bas8[(size_t)j1 * 8 + sg];
            kv = kidb[(size_t)j1 * 8 + sg];
        }
        float4* slot = (float4*)&s_node[kc * CIN + choff];
        float4 ov = *slot;
        ov.x = fmaf(bc, hc.x, ov.x);
        ov.y = fmaf(bc, hc.y, ov.y);
        ov.z = fmaf(bc, hc.z, ov.z);
        ov.w = fmaf(bc, hc.w, ov.w);
        *slot = ov;
    }
    unsigned int* dstp = (unsigned int*)abuf + (size_t)n_local * ((ACC + CIN) / 2);
    for (int l = lane; l < KTOT * 16; l += 64) {
        int k = l >> 4, cp = l & 15;
        const float2 v = *(const float2*)&s_node[k * CIN + cp * 2];
        dstp[k * (CIN / 2) + cp] = pack_bf16x2(v.x, v.y);
    }
    if (lane < 16) {
        const float2 v = *(const float2*)&h[(size_t)n * CIN + lane * 2];
        dstp[ACC / 2 + lane] = pack_bf16x2(v.x, v.y);
    }
}

// ---------------------------------------------------------------------------
// Layer-3 accumulate via MFMA: one wave per node.
// acc[48][64] = sum over 32-edge chunks of Bt[48 x 32] @ H[32 x 64], where
// Bt[k][jj] = bf16(basis) scattered into LDS (within-edge k's distinct =>
// race-free), H read directly from L2-resident bf16 h2.
// A-frag: A[m=lane&15][k=q*8+j] = Bt[mt*16+m][q*8+j] (row stride 40 to dodge
// bank conflicts). B-frag: B[k=q*8+j][n=lane&15] = h2bf[src[q*8+j]][nt*16+n].
// Accumulator: 12 f32x4 tiles in regs. Emits bf16 row [acc(3072) | h2(64)].
// ---------------------------------------------------------------------------
#define BTSTRIDE 40
__global__ __launch_bounds__(256) void mfma_acc3_kernel(
    const int* __restrict__ srcs, const float* __restrict__ bas8,
    const unsigned char* __restrict__ kidb, const int* __restrict__ row_start,
    const unsigned short* __restrict__ h2bf, unsigned short* __restrict__ abuf,
    int n0, int mc) {
    __shared__ unsigned short BtAll[4][KTOT * BTSTRIDE];  // 3.75 KB/wave
    int w = threadIdx.x >> 6, lane = threadIdx.x & 63;
    int n_local = blockIdx.x * 4 + w;
    if (n_local >= mc) return;
    int n = n0 + n_local;
    unsigned short* Bt = &BtAll[w][0];
    int q = lane >> 4;
    int l15 = lane & 15;
    int beg = row_start[n], end = row_start[n + 1];
    int cnt = end - beg;
    f32x4 acc[3][4] = {};

    for (int c0 = 0; c0 < cnt; c0 += 32) {
        // zero Bt (48*40 ushort = 3840 B = 240 uint4)
        uint4 z = make_uint4(0, 0, 0, 0);
        for (int l = lane; l < (KTOT * BTSTRIDE) / 8; l += 64) ((uint4*)Bt)[l] = z;
        // scatter bf16 basis: 32 edges x 8 splines
#pragma unroll
        for (int it = 0; it < 4; ++it) {
            int idx = it * 64 + lane;     // jj*8 + s
            int jj = idx >> 3, s = idx & 7;
            int j = c0 + jj;
            if (j < cnt) {
                float b = bas8[(size_t)(beg + j) * 8 + s];
                int k = kidb[(size_t)(beg + j) * 8 + s];
                Bt[k * BTSTRIDE + jj] = bf16_rne(b);
            }
        }
        // per-lane source indices for this lane's k-rows (jj = q*8+j), clamped
        int srcv[8];
#pragma unroll
        for (int j = 0; j < 8; ++j) {
            int jc = c0 + q * 8 + j;
            jc = (jc < cnt) ? jc : (cnt - 1);
            srcv[j] = srcs[beg + jc];
        }
        // A-frags (ds_read after ds_write: in-order DS pipe within wave)
        bf16x8 afr[3];
#pragma unroll
        for (int mt = 0; mt < 3; ++mt) {
            uint4 raw = *(const uint4*)&Bt[(mt * 16 + l15) * BTSTRIDE + q * 8];
            afr[mt] = __builtin_bit_cast(bf16x8, raw);
        }
        // B-frags from global h2bf + MFMA
#pragma unroll
        for (int nt = 0; nt < 4; ++nt) {
            unsigned int bw[4];
#pragma unroll
            for (int jp = 0; jp < 4; ++jp) {
                unsigned int lo = h2bf[(size_t)srcv[2 * jp] * 64 + nt * 16 + l15];
                unsigned int hi = h2bf[(size_t)srcv[2 * jp + 1] * 64 + nt * 16 + l15];
                bw[jp] = lo | (hi << 16);
            }
            uint4 braw = make_uint4(bw[0], bw[1], bw[2], bw[3]);
            bf16x8 bfr = __builtin_bit_cast(bf16x8, braw);
#pragma unroll
            for (int mt = 0; mt < 3; ++mt)
                acc[mt][nt] = __builtin_amdgcn_mfma_f32_16x16x32_bf16(afr[mt], bfr,
                                                                      acc[mt][nt], 0, 0, 0);
        }
    }

    // writeout: kk = mt*16 + q*4 + r, ch = nt*16 + l15
    unsigned short* arow = abuf + (size_t)n_local * 3136;
#pragma unroll
    for (int mt = 0; mt < 3; ++mt)
#pragma unroll
        for (int nt = 0; nt < 4; ++nt)
#pragma unroll
            for (int r = 0; r < 4; ++r) {
                int kk = mt * 16 + q * 4 + r;
                int ch = nt * 16 + l15;
                arow[kk * 64 + ch] = bf16_rne(acc[mt][nt][r]);
            }
    // h_prev tail (already bf16)
    arow[3072 + lane] = h2bf[(size_t)n * 64 + lane];
}

// ---------------------------------------------------------------------------
// Pack W' = [W(KK rows); root(CP rows)] into MFMA B-fragment order.
// ---------------------------------------------------------------------------
__global__ void pack_w_kernel(const float* __restrict__ W, const float* __restrict__ root,
                              int KK, int NN, int total, unsigned short* __restrict__ Wp) {
    int tid = blockIdx.x * 256 + threadIdx.x;
    if (tid >= total) return;
    int nct = NN >> 4;
    int l = tid & 63;
    int c = (tid >> 6) % nct;
    int t = tid / (64 * nct);
    int n = c * 16 + (l & 15);
    int kbase = t * 32 + ((l >> 4) << 3);
    unsigned short vals[8];
#pragma unroll
    for (int jj = 0; jj < 8; ++jj) {
        int k = kbase + jj;
        float v = (k < KK) ? W[(size_t)k * NN + n] : root[(size_t)(k - KK) * NN + n];
        vals[jj] = bf16_rne(v);
    }
    *(uint4*)&Wp[(size_t)tid * 8] = *(uint4*)vals;
}

// ---------------------------------------------------------------------------
// MFMA GEMM: out[n0+r, :NN] = relu( Arow[r,:Kp](bf16) @ W'[Kp,NN] + bias ).
// BF16OUT: write bf16 (for h2), else fp32 (final logits).
// ---------------------------------------------------------------------------
template <int NCT, bool BF16OUT>
__global__ __launch_bounds__(256) void mfma_gemm(
    const unsigned short* __restrict__ A, const unsigned short* __restrict__ Wp,
    const float* __restrict__ bias, void* __restrict__ outp,
    int Kp, int n0, int mc) {
    constexpr int NN = NCT * 16;
    int w = threadIdx.x >> 6, lane = threadIdx.x & 63;
    int row_local = blockIdx.x * 64 + w * 16 + (lane & 15);
    int row_c = min(row_local, mc - 1);
    const unsigned short* arow = A + (size_t)row_c * Kp + ((lane >> 4) << 3);
    const uint4* wpq = (const uint4*)Wp;
    f32x4 acc[NCT] = {};
    int tsteps = Kp >> 5;
    for (int t = 0; t < tsteps; ++t) {
        uint4 araw = *(const uint4*)(arow + t * 32);
        bf16x8 af = __builtin_bit_cast(bf16x8, araw);
        const uint4* bbase = wpq + ((size_t)t * NCT) * 64 + lane;
#pragma unroll
        for (int c = 0; c < NCT; ++c) {
            uint4 braw = bbase[c * 64];
            bf16x8 bfr = __builtin_bit_cast(bf16x8, braw);
            acc[c] = __builtin_amdgcn_mfma_f32_16x16x32_bf16(af, bfr, acc[c], 0, 0, 0);
        }
    }
    int col0 = lane & 15;
    int rbase = blockIdx.x * 64 + w * 16 + ((lane >> 4) << 2);
#pragma unroll
    for (int c = 0; c < NCT; ++c) {
        int col = c * 16 + col0;
        float bv = bias[col];
#pragma unroll
        for (int r = 0; r < 4; ++r) {
            int rowo = rbase + r;
            if (rowo < mc) {
                float v = fmaxf(acc[c][r] + bv, 0.0f);
                if (BF16OUT)
                    ((unsigned short*)outp)[(size_t)(n0 + rowo) * NN + col] = bf16_rne(v);
                else
                    ((float*)outp)[(size_t)(n0 + rowo) * NN + col] = v;
            }
        }
    }
}

// ---------------------------------------------------------------------------
// log_softmax over rows of out[N,128], in place. One wave per row.
// ---------------------------------------------------------------------------
__global__ void logsoftmax_kernel(float* __restrict__ out) {
    int n = blockIdx.x;
    int lane = threadIdx.x;
    float v0 = out[(size_t)n * 128 + lane];
    float v1 = out[(size_t)n * 128 + 64 + lane];
    float m = fmaxf(v0, v1);
#pragma unroll
    for (int off = 32; off > 0; off >>= 1) m = fmaxf(m, __shfl_xor(m, off));
    float s = expf(v0 - m) + expf(v1 - m);
#pragma unroll
    for (int off = 32; off > 0; off >>= 1) s += __shfl_xor(s, off);
    float lse = m + logf(s);
    out[(size_t)n * 128 + lane] = v0 - lse;
    out[(size_t)n * 128 + 64 + lane] = v1 - lse;
}

// ---------------------------------------------------------------------------
// Launch
// ---------------------------------------------------------------------------
extern "C" void kernel_launch(void* const* d_in, const int* in_sizes, int n_in,
                              void* d_out, int out_size, void* d_ws, size_t ws_size,
                              hipStream_t stream) {
    const float* x = (const float*)d_in[0];
    const int* ei = (const int*)d_in[1];
    const float* pseudo = (const float*)d_in[2];
    const float* W1 = (const float*)d_in[3];
    const float* root1 = (const float*)d_in[4];
    const float* b1 = (const float*)d_in[5];
    const float* W2 = (const float*)d_in[6];
    const float* root2 = (const float*)d_in[7];
    const float* b2 = (const float*)d_in[8];
    const float* W3 = (const float*)d_in[9];
    const float* root3 = (const float*)d_in[10];
    const float* b3 = (const float*)d_in[11];
    float* out = (float*)d_out;
    char* ws = (char*)d_ws;

    const int N = NN_NODES, E = NE_EDGES;
    const int Kp2 = 49 * 32;   // 1568
    const int Kp3 = 49 * 64;   // 3136
    size_t off = 0;
    auto carve = [&](size_t bytes) {
        size_t p = off;
        off += (bytes + 255) & ~(size_t)255;
        return p;
    };
    int* counts = (int*)(ws + carve((size_t)N * 4 * 2));
    int* cursor = counts + N;
    int* row_start = (int*)(ws + carve((size_t)(N + 1) * 4));
    int* slot_pos = (int*)(ws + carve((size_t)E * 4));
    int* srcs = (int*)(ws + carve((size_t)E * 4));
    float* bas8 = (float*)(ws + carve((size_t)E * 8 * 4));
    unsigned char* kidb = (unsigned char*)(ws + carve((size_t)E * 8));
    float* h1 = (float*)(ws + carve((size_t)N * 32 * 4));
    unsigned short* h2bf = (unsigned short*)(ws + carve((size_t)N * 64 * 2));
    unsigned short* Wp2 = (unsigned short*)(ws + carve((size_t)Kp2 * 64 * 2));
    unsigned short* Wp3 = (unsigned short*)(ws + carve((size_t)Kp3 * 128 * 2));
    size_t rem = (ws_size > off) ? (ws_size - off) : 0;
    unsigned short* abuf = (unsigned short*)(ws + off);

    int ch2 = (int)(rem / ((size_t)Kp2 * 2));
    int ch3 = (int)(rem / ((size_t)Kp3 * 2));
    if (ch2 > N) ch2 = N;
    if (ch3 > N) ch3 = N;
    if (ch2 < 1) ch2 = 1;
    if (ch3 < 1) ch3 = 1;

    int egrid = (E + 255) / 256;

    // CSR + sorted edge metadata
    zero_kernel<<<(2 * N + 255) / 256, 256, 0, stream>>>(counts, 2 * N);
    count_kernel<<<egrid, 256, 0, stream>>>(ei, counts);
    scan_kernel<<<1, 256, 0, stream>>>(counts, row_start);
    fill_kernel<<<egrid, 256, 0, stream>>>(ei, row_start, cursor, slot_pos);
    edge_prep_sorted<<<egrid, 256, 0, stream>>>(pseudo, ei, slot_pos, srcs, bas8, kidb);

    // pack weights (bf16 MFMA B-fragment order)
    int tot2 = (Kp2 / 32) * (64 / 16) * 64;
    int tot3 = (Kp3 / 32) * (128 / 16) * 64;
    pack_w_kernel<<<(tot2 + 255) / 256, 256, 0, stream>>>(W2, root2, KTOT * 32, 64, tot2, Wp2);
    pack_w_kernel<<<(tot3 + 255) / 256, 256, 0, stream>>>(W3, root3, KTOT * 64, 128, tot3, Wp3);

    // layer 1 (fused accumulate + dense + relu)
    layer1_fused_kernel<<<(N + 3) / 4, 256, 0, stream>>>(srcs, bas8, kidb, row_start, x,
                                                         W1, root1, b1, h1);

    // layer 2 (scalar LDS accumulate, round-6 body) -> bf16 h2
    for (int n0 = 0; n0 < N; n0 += ch2) {
        int mc = N - n0 < ch2 ? N - n0 : ch2;
        accumulate2_kernel<<<(mc + 3) / 4, 256, 0, stream>>>(
            srcs, bas8, kidb, row_start, h1, abuf, n0, mc);
        mfma_gemm<4, true><<<(mc + 63) / 64, 256, 0, stream>>>(abuf, Wp2, b2, h2bf,
                                                               Kp2, n0, mc);
    }

    // layer 3 (MFMA accumulate) -> logits
    for (int n0 = 0; n0 < N; n0 += ch3) {
        int mc = N - n0 < ch3 ? N - n0 : ch3;
        mfma_acc3_kernel<<<(mc + 3) / 4, 256, 0, stream>>>(
            srcs, bas8, kidb, row_start, h2bf, abuf, n0, mc);
        mfma_gemm<8, false><<<(mc + 63) / 64, 256, 0, stream>>>(abuf, Wp3, b3, out,
                                                                Kp3, n0, mc);
    }

    logsoftmax_kernel<<<N, 64, 0, stream>>>(out);
}

// Round 9
// 370.545 us; speedup vs baseline: 9.8366x; 1.1367x over previous
//
#include <hip/hip_runtime.h>
#include <hip/hip_bf16.h>

#define NN_NODES 20000
#define NE_EDGES 500000
#define KTOT 48

typedef __bf16 bf16x8 __attribute__((ext_vector_type(8)));
typedef float f32x4 __attribute__((ext_vector_type(4)));

__device__ inline unsigned short bf16_rne(float x) {
    unsigned int u = __float_as_uint(x);
    u = (u + 0x7fffu + ((u >> 16) & 1u)) >> 16;
    return (unsigned short)u;
}
__device__ inline unsigned int pack_bf16x2(float a, float b) {
    return (unsigned int)bf16_rne(a) | ((unsigned int)bf16_rne(b) << 16);
}

// ---------------------------------------------------------------------------
// Zero helper
// ---------------------------------------------------------------------------
__global__ void zero_kernel(int* __restrict__ p, int n) {
    int i = blockIdx.x * 256 + threadIdx.x;
    if (i < n) p[i] = 0;
}

// ---------------------------------------------------------------------------
// CSR build
// ---------------------------------------------------------------------------
__global__ void count_kernel(const int* __restrict__ ei, int* __restrict__ counts) {
    int e = blockIdx.x * 256 + threadIdx.x;
    if (e < NE_EDGES) atomicAdd(&counts[ei[NE_EDGES + e]], 1);
}

__global__ void scan_kernel(const int* __restrict__ counts, int* __restrict__ row_start) {
    __shared__ int part[256];
    const int CH = (NN_NODES + 255) / 256;
    int t = threadIdx.x;
    int begin = t * CH;
    int end = begin + CH;
    if (end > NN_NODES) end = NN_NODES;
    int sum = 0;
    for (int i = begin; i < end && i < NN_NODES; ++i) sum += counts[i];
    part[t] = sum;
    __syncthreads();
    for (int off = 1; off < 256; off <<= 1) {
        int v = (t >= off) ? part[t - off] : 0;
        __syncthreads();
        part[t] += v;
        __syncthreads();
    }
    int run = (t == 0) ? 0 : part[t - 1];
    for (int i = begin; i < end && i < NN_NODES; ++i) {
        row_start[i] = run;
        run += counts[i];
    }
    if (t == 255) row_start[NN_NODES] = part[255];
}

__global__ void fill_kernel(const int* __restrict__ ei, const int* __restrict__ row_start,
                            int* __restrict__ cursor, int* __restrict__ slot_pos) {
    int e = blockIdx.x * 256 + threadIdx.x;
    if (e < NE_EDGES) {
        int d = ei[NE_EDGES + e];
        int p = atomicAdd(&cursor[d], 1);
        slot_pos[e] = row_start[d] + p;
    }
}

// ---------------------------------------------------------------------------
// Edge prep (CSR slot order). All 8 kidx of an edge pairwise DISTINCT
// (clamped zero-weight corners redirected) => non-atomic LDS writes/RMW safe.
// ---------------------------------------------------------------------------
__global__ void edge_prep_sorted(const float* __restrict__ pseudo, const int* __restrict__ ei,
                                 const int* __restrict__ slot_pos,
                                 int* __restrict__ srcs,
                                 float* __restrict__ bas8, unsigned char* __restrict__ kidb) {
    int e = blockIdx.x * 256 + threadIdx.x;
    if (e >= NE_EDGES) return;
    const int ksa[3] = {3, 8, 2};
    float frac[3];
    int id_lo[3], id_hi[3];
#pragma unroll
    for (int d = 0; d < 3; ++d) {
        float u = pseudo[e * 3 + d] * (1.0f / 4.5f);
        u = fminf(fmaxf(u, 0.0f), 1.0f);
        float pos = u * (float)(ksa[d] - 1);
        float fl = floorf(pos);
        int lo = (int)fl;
        frac[d] = pos - fl;
        id_lo[d] = lo;
        id_hi[d] = (lo + 1 <= ksa[d] - 1) ? lo + 1 : lo - 1;
    }
    int j = slot_pos[e];
    srcs[j] = ei[e];
#pragma unroll
    for (int s = 0; s < 8; ++s) {
        float w = 1.0f;
        int k = 0;
        const int strides[3] = {16, 2, 1};
#pragma unroll
        for (int d = 0; d < 3; ++d) {
            int bit = (s >> d) & 1;
            k += (bit ? id_hi[d] : id_lo[d]) * strides[d];
            w *= bit ? frac[d] : (1.0f - frac[d]);
        }
        bas8[(size_t)j * 8 + s] = w;
        kidb[(size_t)j * 8 + s] = (unsigned char)k;
    }
}

// ---------------------------------------------------------------------------
// Layer 1 FUSED (c_in = 1): wave per node, 8 edges x 8 splines in parallel.
// Emits h1 in BF16 (consumed by the layer-2 MFMA accumulate).
// ---------------------------------------------------------------------------
__global__ __launch_bounds__(256) void layer1_fused_kernel(
    const int* __restrict__ srcs, const float* __restrict__ bas8,
    const unsigned char* __restrict__ kidb, const int* __restrict__ row_start,
    const float* __restrict__ x, const float* __restrict__ W1,
    const float* __restrict__ root1, const float* __restrict__ b1,
    unsigned short* __restrict__ h1bf) {
    __shared__ float w1s[KTOT * 32];
    __shared__ float scopy[4][8 * 49];
    int tid = threadIdx.x;
    for (int l = tid; l < KTOT * 32; l += 256) w1s[l] = W1[l];
    int w = tid >> 6, lane = tid & 63;
    int n = blockIdx.x * 4 + w;
    bool act = n < NN_NODES;
    float* sc = &scopy[w][0];
    for (int l = lane; l < 8 * 49; l += 64) sc[l] = 0.0f;
    if (act) {
        int beg = row_start[n], end = row_start[n + 1];
        int es = lane >> 3;
        for (int jb = beg; jb < end; jb += 8) {
            int j = jb + es;
            if (j < end) {
                float b = bas8[(size_t)jb * 8 + lane];
                int k = kidb[(size_t)jb * 8 + lane];
                float xv = x[srcs[j]];
                sc[es * 49 + k] += b * xv;
            }
        }
        if (lane < KTOT) {
            float a = 0.0f;
#pragma unroll
            for (int e = 0; e < 8; ++e) a += sc[e * 49 + lane];
            sc[lane] = a;
        }
    }
    __syncthreads();
    if (act && lane < 32) {
        float s = b1[lane] + x[n] * root1[lane];
#pragma unroll 8
        for (int k = 0; k < KTOT; ++k) s = fmaf(sc[k], w1s[k * 32 + lane], s);
        h1bf[n * 32 + lane] = bf16_rne(fmaxf(s, 0.0f));
    }
}

// ---------------------------------------------------------------------------
// Accumulate via MFMA (layers 2 and 3): one wave per node.
// acc[48][CIN] = sum over 32-edge chunks of Bt[48 x 32] @ H[32 x CIN], where
// Bt[k][jj] = bf16(basis) scattered into LDS (within-edge k's distinct =>
// race-free), H read directly from L2-resident bf16 h.
// A-frag: A[m=lane&15][k=q*8+j] = Bt[mt*16+m][q*8+j] (row stride 40 dodges
// bank conflicts). B-frag: B[k=q*8+j][n=lane&15] = hbf[src[q*8+j]][nt*16+n].
// Emits bf16 row [acc(48*CIN) | h_prev(CIN)] -> Kp = 49*CIN.
// ---------------------------------------------------------------------------
#define BTSTRIDE 40
template <int CIN>
__global__ __launch_bounds__(256) void mfma_acc_kernel(
    const int* __restrict__ srcs, const float* __restrict__ bas8,
    const unsigned char* __restrict__ kidb, const int* __restrict__ row_start,
    const unsigned short* __restrict__ hbf, unsigned short* __restrict__ abuf,
    int n0, int mc) {
    constexpr int NT = CIN / 16;
    __shared__ unsigned short BtAll[4][KTOT * BTSTRIDE];  // 3.75 KB/wave
    int w = threadIdx.x >> 6, lane = threadIdx.x & 63;
    int n_local = blockIdx.x * 4 + w;
    if (n_local >= mc) return;
    int n = n0 + n_local;
    unsigned short* Bt = &BtAll[w][0];
    int q = lane >> 4;
    int l15 = lane & 15;
    int beg = row_start[n], end = row_start[n + 1];
    int cnt = end - beg;
    f32x4 acc[3][NT] = {};

    for (int c0 = 0; c0 < cnt; c0 += 32) {
        // zero Bt (48*40 ushort = 3840 B = 240 uint4)
        uint4 z = make_uint4(0, 0, 0, 0);
        for (int l = lane; l < (KTOT * BTSTRIDE) / 8; l += 64) ((uint4*)Bt)[l] = z;
        // scatter bf16 basis: 32 edges x 8 splines
#pragma unroll
        for (int it = 0; it < 4; ++it) {
            int idx = it * 64 + lane;     // jj*8 + s
            int jj = idx >> 3, s = idx & 7;
            int j = c0 + jj;
            if (j < cnt) {
                float b = bas8[(size_t)(beg + j) * 8 + s];
                int k = kidb[(size_t)(beg + j) * 8 + s];
                Bt[k * BTSTRIDE + jj] = bf16_rne(b);
            }
        }
        // per-lane source indices for this lane's k-rows (jj = q*8+j), clamped
        int srcv[8];
#pragma unroll
        for (int j = 0; j < 8; ++j) {
            int jc = c0 + q * 8 + j;
            jc = (jc < cnt) ? jc : (cnt - 1);
            srcv[j] = srcs[beg + jc];
        }
        // A-frags (ds_read after ds_write: in-order DS pipe within wave)
        bf16x8 afr[3];
#pragma unroll
        for (int mt = 0; mt < 3; ++mt) {
            uint4 raw = *(const uint4*)&Bt[(mt * 16 + l15) * BTSTRIDE + q * 8];
            afr[mt] = __builtin_bit_cast(bf16x8, raw);
        }
        // B-frags from global hbf + MFMA
#pragma unroll
        for (int nt = 0; nt < NT; ++nt) {
            unsigned int bw[4];
#pragma unroll
            for (int jp = 0; jp < 4; ++jp) {
                unsigned int lo = hbf[(size_t)srcv[2 * jp] * CIN + nt * 16 + l15];
                unsigned int hi = hbf[(size_t)srcv[2 * jp + 1] * CIN + nt * 16 + l15];
                bw[jp] = lo | (hi << 16);
            }
            uint4 braw = make_uint4(bw[0], bw[1], bw[2], bw[3]);
            bf16x8 bfr = __builtin_bit_cast(bf16x8, braw);
#pragma unroll
            for (int mt = 0; mt < 3; ++mt)
                acc[mt][nt] = __builtin_amdgcn_mfma_f32_16x16x32_bf16(afr[mt], bfr,
                                                                      acc[mt][nt], 0, 0, 0);
        }
    }

    // writeout: kk = mt*16 + q*4 + r, ch = nt*16 + l15
    unsigned short* arow = abuf + (size_t)n_local * (49 * CIN);
#pragma unroll
    for (int mt = 0; mt < 3; ++mt)
#pragma unroll
        for (int nt = 0; nt < NT; ++nt)
#pragma unroll
            for (int r = 0; r < 4; ++r) {
                int kk = mt * 16 + q * 4 + r;
                int ch = nt * 16 + l15;
                arow[kk * CIN + ch] = bf16_rne(acc[mt][nt][r]);
            }
    // h_prev tail (already bf16)
    if (lane < CIN) arow[KTOT * CIN + lane] = hbf[(size_t)n * CIN + lane];
}

// ---------------------------------------------------------------------------
// Pack W' = [W(KK rows); root(CP rows)] into MFMA B-fragment order.
// ---------------------------------------------------------------------------
__global__ void pack_w_kernel(const float* __restrict__ W, const float* __restrict__ root,
                              int KK, int NN, int total, unsigned short* __restrict__ Wp) {
    int tid = blockIdx.x * 256 + threadIdx.x;
    if (tid >= total) return;
    int nct = NN >> 4;
    int l = tid & 63;
    int c = (tid >> 6) % nct;
    int t = tid / (64 * nct);
    int n = c * 16 + (l & 15);
    int kbase = t * 32 + ((l >> 4) << 3);
    unsigned short vals[8];
#pragma unroll
    for (int jj = 0; jj < 8; ++jj) {
        int k = kbase + jj;
        float v = (k < KK) ? W[(size_t)k * NN + n] : root[(size_t)(k - KK) * NN + n];
        vals[jj] = bf16_rne(v);
    }
    *(uint4*)&Wp[(size_t)tid * 8] = *(uint4*)vals;
}

// ---------------------------------------------------------------------------
// MFMA GEMM: out[n0+r, :NN] = relu( Arow[r,:Kp](bf16) @ W'[Kp,NN] + bias ).
// BF16OUT: write bf16 (for h2), else fp32 (final logits).
// ---------------------------------------------------------------------------
template <int NCT, bool BF16OUT>
__global__ __launch_bounds__(256) void mfma_gemm(
    const unsigned short* __restrict__ A, const unsigned short* __restrict__ Wp,
    const float* __restrict__ bias, void* __restrict__ outp,
    int Kp, int n0, int mc) {
    constexpr int NN = NCT * 16;
    int w = threadIdx.x >> 6, lane = threadIdx.x & 63;
    int row_local = blockIdx.x * 64 + w * 16 + (lane & 15);
    int row_c = min(row_local, mc - 1);
    const unsigned short* arow = A + (size_t)row_c * Kp + ((lane >> 4) << 3);
    const uint4* wpq = (const uint4*)Wp;
    f32x4 acc[NCT] = {};
    int tsteps = Kp >> 5;
    for (int t = 0; t < tsteps; ++t) {
        uint4 araw = *(const uint4*)(arow + t * 32);
        bf16x8 af = __builtin_bit_cast(bf16x8, araw);
        const uint4* bbase = wpq + ((size_t)t * NCT) * 64 + lane;
#pragma unroll
        for (int c = 0; c < NCT; ++c) {
            uint4 braw = bbase[c * 64];
            bf16x8 bfr = __builtin_bit_cast(bf16x8, braw);
            acc[c] = __builtin_amdgcn_mfma_f32_16x16x32_bf16(af, bfr, acc[c], 0, 0, 0);
        }
    }
    int col0 = lane & 15;
    int rbase = blockIdx.x * 64 + w * 16 + ((lane >> 4) << 2);
#pragma unroll
    for (int c = 0; c < NCT; ++c) {
        int col = c * 16 + col0;
        float bv = bias[col];
#pragma unroll
        for (int r = 0; r < 4; ++r) {
            int rowo = rbase + r;
            if (rowo < mc) {
                float v = fmaxf(acc[c][r] + bv, 0.0f);
                if (BF16OUT)
                    ((unsigned short*)outp)[(size_t)(n0 + rowo) * NN + col] = bf16_rne(v);
                else
                    ((float*)outp)[(size_t)(n0 + rowo) * NN + col] = v;
            }
        }
    }
}

// ---------------------------------------------------------------------------
// log_softmax over rows of out[N,128], in place. One wave per row.
// ---------------------------------------------------------------------------
__global__ void logsoftmax_kernel(float* __restrict__ out) {
    int n = blockIdx.x;
    int lane = threadIdx.x;
    float v0 = out[(size_t)n * 128 + lane];
    float v1 = out[(size_t)n * 128 + 64 + lane];
    float m = fmaxf(v0, v1);
#pragma unroll
    for (int off = 32; off > 0; off >>= 1) m = fmaxf(m, __shfl_xor(m, off));
    float s = expf(v0 - m) + expf(v1 - m);
#pragma unroll
    for (int off = 32; off > 0; off >>= 1) s += __shfl_xor(s, off);
    float lse = m + logf(s);
    out[(size_t)n * 128 + lane] = v0 - lse;
    out[(size_t)n * 128 + 64 + lane] = v1 - lse;
}

// ---------------------------------------------------------------------------
// Launch
// ---------------------------------------------------------------------------
extern "C" void kernel_launch(void* const* d_in, const int* in_sizes, int n_in,
                              void* d_out, int out_size, void* d_ws, size_t ws_size,
                              hipStream_t stream) {
    const float* x = (const float*)d_in[0];
    const int* ei = (const int*)d_in[1];
    const float* pseudo = (const float*)d_in[2];
    const float* W1 = (const float*)d_in[3];
    const float* root1 = (const float*)d_in[4];
    const float* b1 = (const float*)d_in[5];
    const float* W2 = (const float*)d_in[6];
    const float* root2 = (const float*)d_in[7];
    const float* b2 = (const float*)d_in[8];
    const float* W3 = (const float*)d_in[9];
    const float* root3 = (const float*)d_in[10];
    const float* b3 = (const float*)d_in[11];
    float* out = (float*)d_out;
    char* ws = (char*)d_ws;

    const int N = NN_NODES, E = NE_EDGES;
    const int Kp2 = 49 * 32;   // 1568
    const int Kp3 = 49 * 64;   // 3136
    size_t off = 0;
    auto carve = [&](size_t bytes) {
        size_t p = off;
        off += (bytes + 255) & ~(size_t)255;
        return p;
    };
    int* counts = (int*)(ws + carve((size_t)N * 4 * 2));
    int* cursor = counts + N;
    int* row_start = (int*)(ws + carve((size_t)(N + 1) * 4));
    int* slot_pos = (int*)(ws + carve((size_t)E * 4));
    int* srcs = (int*)(ws + carve((size_t)E * 4));
    float* bas8 = (float*)(ws + carve((size_t)E * 8 * 4));
    unsigned char* kidb = (unsigned char*)(ws + carve((size_t)E * 8));
    unsigned short* h1bf = (unsigned short*)(ws + carve((size_t)N * 32 * 2));
    unsigned short* h2bf = (unsigned short*)(ws + carve((size_t)N * 64 * 2));
    unsigned short* Wp2 = (unsigned short*)(ws + carve((size_t)Kp2 * 64 * 2));
    unsigned short* Wp3 = (unsigned short*)(ws + carve((size_t)Kp3 * 128 * 2));
    size_t rem = (ws_size > off) ? (ws_size - off) : 0;
    unsigned short* abuf = (unsigned short*)(ws + off);

    int ch2 = (int)(rem / ((size_t)Kp2 * 2));
    int ch3 = (int)(rem / ((size_t)Kp3 * 2));
    if (ch2 > N) ch2 = N;
    if (ch3 > N) ch3 = N;
    if (ch2 < 1) ch2 = 1;
    if (ch3 < 1) ch3 = 1;

    int egrid = (E + 255) / 256;

    // CSR + sorted edge metadata
    zero_kernel<<<(2 * N + 255) / 256, 256, 0, stream>>>(counts, 2 * N);
    count_kernel<<<egrid, 256, 0, stream>>>(ei, counts);
    scan_kernel<<<1, 256, 0, stream>>>(counts, row_start);
    fill_kernel<<<egrid, 256, 0, stream>>>(ei, row_start, cursor, slot_pos);
    edge_prep_sorted<<<egrid, 256, 0, stream>>>(pseudo, ei, slot_pos, srcs, bas8, kidb);

    // pack weights (bf16 MFMA B-fragment order)
    int tot2 = (Kp2 / 32) * (64 / 16) * 64;
    int tot3 = (Kp3 / 32) * (128 / 16) * 64;
    pack_w_kernel<<<(tot2 + 255) / 256, 256, 0, stream>>>(W2, root2, KTOT * 32, 64, tot2, Wp2);
    pack_w_kernel<<<(tot3 + 255) / 256, 256, 0, stream>>>(W3, root3, KTOT * 64, 128, tot3, Wp3);

    // layer 1 (fused accumulate + dense + relu) -> bf16 h1
    layer1_fused_kernel<<<(N + 3) / 4, 256, 0, stream>>>(srcs, bas8, kidb, row_start, x,
                                                         W1, root1, b1, h1bf);

    // layer 2 (MFMA accumulate) -> bf16 h2
    for (int n0 = 0; n0 < N; n0 += ch2) {
        int mc = N - n0 < ch2 ? N - n0 : ch2;
        mfma_acc_kernel<32><<<(mc + 3) / 4, 256, 0, stream>>>(
            srcs, bas8, kidb, row_start, h1bf, abuf, n0, mc);
        mfma_gemm<4, true><<<(mc + 63) / 64, 256, 0, stream>>>(abuf, Wp2, b2, h2bf,
                                                               Kp2, n0, mc);
    }

    // layer 3 (MFMA accumulate) -> logits
    for (int n0 = 0; n0 < N; n0 += ch3) {
        int mc = N - n0 < ch3 ? N - n0 : ch3;
        mfma_acc_kernel<64><<<(mc + 3) / 4, 256, 0, stream>>>(
            srcs, bas8, kidb, row_start, h2bf, abuf, n0, mc);
        mfma_gemm<8, false><<<(mc + 63) / 64, 256, 0, stream>>>(abuf, Wp3, b3, out,
                                                                Kp3, n0, mc);
    }

    logsoftmax_kernel<<<N, 64, 0, stream>>>(out);
}